// Round 2
// baseline (1860.120 us; speedup 1.0000x reference)
//
#include <hip/hip_runtime.h>
#include <hip/hip_fp16.h>
#include <cmath>

// ---------------- problem constants (compile-time) ----------------
constexpr int NUSER = 100000;
constexpr int NNEWS = 20000;
constexpr int CH    = 128;      // channels
constexpr int NE    = 250000;   // edges per relation

// ---------------- workspace layout (units: floats) ----------------
// Total ~176 MB (was 292 MB -> suspected ws overflow / memory fault in R1).
constexpr size_t OFF_QU  = 0;                                  // q_user   [NUSER*CH] f32
constexpr size_t OFF_QN  = OFF_QU  + (size_t)NUSER * CH;       // q_news   [NNEWS*CH] f32
constexpr size_t OFF_AGU = OFF_QN  + (size_t)NNEWS * CH;       // agg_user [NUSER*CH] f32
constexpr size_t OFF_AGN = OFF_AGU + (size_t)NUSER * CH;       // agg_news [NNEWS*CH] f32 (contig after agg_user)
constexpr size_t OFF_WKE = OFF_AGN + (size_t)NNEWS * CH;       // Wk_eff [3][128][128] (p_rel/sqrtD folded)
constexpr size_t OFF_BKE = OFF_WKE + 3 * 16384;                // bk_eff [3][128]
constexpr size_t OFF_WVE = OFF_BKE + 3 * 128;                  // Wv_eff [3][128][128]
constexpr size_t OFF_BVE = OFF_WVE + 3 * 16384;                // bv_eff [3][128]
constexpr size_t OFF_KRH = OFF_BVE + 3 * 128;                  // kr fp16 [NUSER*CH] -> NUSER*CH/2 float slots
constexpr size_t OFF_VRH = OFF_KRH + (size_t)NUSER * CH / 2;   // vr fp16 [NUSER*CH]
constexpr size_t OFF_INT = OFF_VRH + (size_t)NUSER * CH / 2;   // int region starts here
// int region offsets (units: ints, relative to OFF_INT)
constexpr size_t IO_RP0  = 0;                    // row_ptr rel0 [NNEWS+1]
constexpr size_t IO_RP1  = IO_RP0 + (NNEWS + 1); // row_ptr rel1 [NUSER+1]
constexpr size_t IO_RP2  = IO_RP1 + (NUSER + 1); // row_ptr rel2 [NUSER+1]
constexpr size_t IO_CUR0 = IO_RP2 + (NUSER + 1); // cursors (contiguous for one zero-fill)
constexpr size_t IO_CUR1 = IO_CUR0 + NNEWS;
constexpr size_t IO_CUR2 = IO_CUR1 + NUSER;
constexpr size_t IO_COL0 = IO_CUR2 + NUSER;      // col (src node per CSR slot)
constexpr size_t IO_COL1 = IO_COL0 + NE;
constexpr size_t IO_COL2 = IO_COL1 + NE;

__device__ __forceinline__ float gelu_f(float x) {
    // exact gelu: 0.5*x*(1+erf(x/sqrt(2)))
    return 0.5f * x * (1.0f + erff(x * 0.70710678118654752440f));
}

// ---------------- zero-fill (replaces hipMemsetAsync: graph-capture-safe for sure) ----------------
__global__ void zero_f4_kernel(float4* __restrict__ p, int n4) {
    int i = blockIdx.x * 256 + threadIdx.x;
    if (i < n4) p[i] = make_float4(0.f, 0.f, 0.f, 0.f);
}
__global__ void zero_i_kernel(int* __restrict__ p, int n) {
    int i = blockIdx.x * 256 + threadIdx.x;
    if (i < n) p[i] = 0;
}

// ---------------- CSR build ----------------
__global__ void hist3_kernel(const int* __restrict__ e0, const int* __restrict__ e1,
                             const int* __restrict__ e2,
                             int* __restrict__ c0, int* __restrict__ c1, int* __restrict__ c2) {
    int idx = blockIdx.x * 256 + threadIdx.x;
    if (idx >= 3 * NE) return;
    int r = idx / NE, e = idx - r * NE;
    const int* ei = (r == 0) ? e0 : (r == 1) ? e1 : e2;
    int*       cu = (r == 0) ? c0 : (r == 1) ? c1 : c2;
    atomicAdd(&cu[ei[NE + e]], 1);   // dst array is second row of [2,E]
}

__global__ __launch_bounds__(1024) void scan3_kernel(int* __restrict__ c0, int* __restrict__ c1,
                                                     int* __restrict__ c2, int* __restrict__ r0,
                                                     int* __restrict__ r1, int* __restrict__ r2) {
    __shared__ int swave[16];
    int rsel = blockIdx.x;
    int* cur = (rsel == 0) ? c0 : (rsel == 1) ? c1 : c2;
    int* rp  = (rsel == 0) ? r0 : (rsel == 1) ? r1 : r2;
    int n    = (rsel == 0) ? NNEWS : NUSER;
    int tid = threadIdx.x, lane = tid & 63, w = tid >> 6;
    int base = 0;
    for (int start = 0; start < n; start += 1024) {
        int i = start + tid;
        int v = (i < n) ? cur[i] : 0;
        int x = v;
        #pragma unroll
        for (int off = 1; off < 64; off <<= 1) {
            int y = __shfl_up(x, off);
            if (lane >= off) x += y;
        }
        if (lane == 63) swave[w] = x;
        __syncthreads();
        if (tid < 16) {
            int t = swave[tid];
            #pragma unroll
            for (int off = 1; off < 16; off <<= 1) {
                int y = __shfl_up(t, off);
                if (tid >= off) t += y;
            }
            swave[tid] = t;
        }
        __syncthreads();
        int woff = (w > 0) ? swave[w - 1] : 0;
        int excl = base + woff + x - v;
        if (i < n) { rp[i] = excl; cur[i] = excl; }  // cur becomes write cursor for fill
        base += swave[15];
        __syncthreads();
    }
    if (tid == 0) rp[n] = base;   // == NE
}

__global__ void fill3_kernel(const int* __restrict__ e0, const int* __restrict__ e1,
                             const int* __restrict__ e2,
                             int* __restrict__ c0, int* __restrict__ c1, int* __restrict__ c2,
                             int* __restrict__ l0, int* __restrict__ l1, int* __restrict__ l2) {
    int idx = blockIdx.x * 256 + threadIdx.x;
    if (idx >= 3 * NE) return;
    int r = idx / NE, e = idx - r * NE;
    const int* ei = (r == 0) ? e0 : (r == 1) ? e1 : e2;
    int*       cu = (r == 0) ? c0 : (r == 1) ? c1 : c2;
    int*       cl = (r == 0) ? l0 : (r == 1) ? l1 : l2;
    int dst = ei[NE + e], src = ei[e];
    int p = atomicAdd(&cu[dst], 1);
    cl[p] = src;
}

// ---------------- effective weight build ----------------
// Wk_eff[r][c][h*32+e] = sum_d Wk[st][c][h*32+d] * a_rel[r][h][d][e]  (* p_rel[r][h]/sqrt(D))
// Wv_eff[r][c][h*32+e] = sum_d Wv[st][c][h*32+d] * m_rel[r][h][d][e]
__global__ void eff_weights_kernel(const float* __restrict__ Wk, const float* __restrict__ bk,
                                   const float* __restrict__ Wv, const float* __restrict__ bv,
                                   const float* __restrict__ a_rel, const float* __restrict__ m_rel,
                                   const float* __restrict__ p_rel,
                                   float* __restrict__ wke, float* __restrict__ bke,
                                   float* __restrict__ wve, float* __restrict__ bve) {
    int b = blockIdx.x;         // 0..5
    int kind = b / 3;           // 0 = K (attention), 1 = V (message)
    int r = b % 3;
    const int st = (r == 1) ? 1 : 0;        // source type per relation
    const float* W   = (kind ? Wv : Wk) + (size_t)st * 16384;
    const float* bi  = (kind ? bv : bk) + (size_t)st * 128;
    const float* rel = (kind ? m_rel : a_rel) + (size_t)r * 4096;
    float* We = (kind ? wve : wke) + (size_t)r * 16384;
    float* be = (kind ? bve : bke) + (size_t)r * 128;
    const float invsq = 0.17677669529663688f;   // 1/sqrt(32)
    for (int o = threadIdx.x; o < 16384; o += 256) {
        int c = o >> 7, col = o & 127, h = col >> 5, e = col & 31;
        const float* wrow = W + (size_t)c * 128 + h * 32;
        const float* rcol = rel + h * 1024 + e;
        float s = 0.f;
        #pragma unroll
        for (int d = 0; d < 32; ++d) s += wrow[d] * rcol[d * 32];
        if (kind == 0) s *= p_rel[r * 4 + h] * invsq;
        We[(size_t)c * 128 + col] = s;
    }
    if (threadIdx.x < 128) {
        int col = threadIdx.x, h = col >> 5, e = col & 31;
        float s = 0.f;
        #pragma unroll
        for (int d = 0; d < 32; ++d) s += bi[h * 32 + d] * rel[h * 1024 + d * 32 + e];
        if (kind == 0) s *= p_rel[r * 4 + h] * invsq;
        be[col] = s;
    }
}

// ---------------- fp32 GEMM: out[n,:] = epi(A[n,:] @ W + bias) ----------------
// 256 threads, 64 rows x 128 cols per block. A fully staged; W staged in 32-row chunks.
// gelu_in: gelu on A load. do_skip: out = relu(sig(skip)*o + (1-sig)*Xold) (in-place safe).
// out_half: store fp16 instead of fp32.
__global__ __launch_bounds__(256) void gemm128_kernel(
    const float* __restrict__ A, const float* __restrict__ W,
    const float* __restrict__ bias, float* __restrict__ Cout, int N,
    int gelu_in, int do_skip, int out_half, const float* __restrict__ skipv,
    const float* __restrict__ Xold)
{
    __shared__ float sA[64 * 132];   // stride 132: breaks bank-conflict, keeps 16B align
    __shared__ float sW[32 * 128];
    const int tid  = threadIdx.x;
    const int row0 = blockIdx.x * 64;

    for (int i = tid; i < 64 * 32; i += 256) {
        int r = i >> 5, q = i & 31;
        int grow = row0 + r;
        float4 v = make_float4(0.f, 0.f, 0.f, 0.f);
        if (grow < N) v = *(const float4*)(A + (size_t)grow * CH + q * 4);
        if (gelu_in) { v.x = gelu_f(v.x); v.y = gelu_f(v.y); v.z = gelu_f(v.z); v.w = gelu_f(v.w); }
        *(float4*)(sA + r * 132 + q * 4) = v;
    }

    float acc[4][8];
    #pragma unroll
    for (int r = 0; r < 4; ++r)
        #pragma unroll
        for (int j = 0; j < 8; ++j) acc[r][j] = 0.f;

    const int cg = tid & 15;   // cols [cg*4 .. +3] and [64+cg*4 .. +3]
    const int rg = tid >> 4;   // rows rg*4 .. rg*4+3

    for (int kt = 0; kt < 4; ++kt) {
        if (kt) __syncthreads();
        for (int i = tid; i < 32 * 32; i += 256) {
            int kr_ = i >> 5, q = i & 31;
            *(float4*)(sW + kr_ * 128 + q * 4) =
                *(const float4*)(W + (size_t)(kt * 32 + kr_) * CH + q * 4);
        }
        __syncthreads();
        #pragma unroll
        for (int kk = 0; kk < 32; kk += 4) {
            float4 av[4];
            #pragma unroll
            for (int r = 0; r < 4; ++r)
                av[r] = *(const float4*)(sA + (rg * 4 + r) * 132 + kt * 32 + kk);
            #pragma unroll
            for (int u = 0; u < 4; ++u) {
                const float* pw = sW + (kk + u) * 128;
                float4 b0 = *(const float4*)(pw + cg * 4);
                float4 b1 = *(const float4*)(pw + 64 + cg * 4);
                #pragma unroll
                for (int r = 0; r < 4; ++r) {
                    float a = (&av[r].x)[u];
                    acc[r][0] = fmaf(a, b0.x, acc[r][0]);
                    acc[r][1] = fmaf(a, b0.y, acc[r][1]);
                    acc[r][2] = fmaf(a, b0.z, acc[r][2]);
                    acc[r][3] = fmaf(a, b0.w, acc[r][3]);
                    acc[r][4] = fmaf(a, b1.x, acc[r][4]);
                    acc[r][5] = fmaf(a, b1.y, acc[r][5]);
                    acc[r][6] = fmaf(a, b1.z, acc[r][6]);
                    acc[r][7] = fmaf(a, b1.w, acc[r][7]);
                }
            }
        }
    }

    float4 bb0 = *(const float4*)(bias + cg * 4);
    float4 bb1 = *(const float4*)(bias + 64 + cg * 4);
    float aS = 0.f, bS = 0.f;
    if (do_skip) {
        float sv = skipv[0];
        aS = 1.0f / (1.0f + expf(-sv));
        bS = 1.0f - aS;
    }
    #pragma unroll
    for (int r = 0; r < 4; ++r) {
        int grow = row0 + rg * 4 + r;
        if (grow >= N) continue;
        float4 o0 = make_float4(acc[r][0] + bb0.x, acc[r][1] + bb0.y,
                                acc[r][2] + bb0.z, acc[r][3] + bb0.w);
        float4 o1 = make_float4(acc[r][4] + bb1.x, acc[r][5] + bb1.y,
                                acc[r][6] + bb1.z, acc[r][7] + bb1.w);
        if (do_skip) {
            float4 x0 = *(const float4*)(Xold + (size_t)grow * CH + cg * 4);
            float4 x1 = *(const float4*)(Xold + (size_t)grow * CH + 64 + cg * 4);
            o0.x = fmaxf(aS * o0.x + bS * x0.x, 0.f);
            o0.y = fmaxf(aS * o0.y + bS * x0.y, 0.f);
            o0.z = fmaxf(aS * o0.z + bS * x0.z, 0.f);
            o0.w = fmaxf(aS * o0.w + bS * x0.w, 0.f);
            o1.x = fmaxf(aS * o1.x + bS * x1.x, 0.f);
            o1.y = fmaxf(aS * o1.y + bS * x1.y, 0.f);
            o1.z = fmaxf(aS * o1.z + bS * x1.z, 0.f);
            o1.w = fmaxf(aS * o1.w + bS * x1.w, 0.f);
        }
        if (out_half) {
            __half2* Ch = (__half2*)Cout;
            size_t rb = (size_t)grow * 64;   // 64 half2 per row
            Ch[rb + cg * 2]      = __floats2half2_rn(o0.x, o0.y);
            Ch[rb + cg * 2 + 1]  = __floats2half2_rn(o0.z, o0.w);
            Ch[rb + 32 + cg * 2]     = __floats2half2_rn(o1.x, o1.y);
            Ch[rb + 32 + cg * 2 + 1] = __floats2half2_rn(o1.z, o1.w);
        } else {
            *(float4*)(Cout + (size_t)grow * CH + cg * 4) = o0;
            *(float4*)(Cout + (size_t)grow * CH + 64 + cg * 4) = o1;
        }
    }
}

// ---------------- fused per-destination attention + aggregation ----------------
// One 128-thread slot per dst node (thread c = channel, head = c>>5). Single pass
// softmax without max-shift (scores are O(1-5): exp() safely in fp32 range).
__global__ __launch_bounds__(256) void attn_kernel(
    const float* __restrict__ q, const __half* __restrict__ kr, const __half* __restrict__ vr,
    const int* __restrict__ row_ptr, const int* __restrict__ col,
    float* __restrict__ agg, int Ndst)
{
    int d = blockIdx.x * 2 + (threadIdx.x >> 7);
    if (d >= Ndst) return;
    int c = threadIdx.x & 127;
    float qc = q[(size_t)d * CH + c];
    int e0 = row_ptr[d], e1 = row_ptr[d + 1];
    float den = 0.f, acc = 0.f;
    for (int e = e0; e < e1; ++e) {
        int s = col[e];
        float kv = __half2float(kr[(size_t)s * CH + c]);
        float vv = __half2float(vr[(size_t)s * CH + c]);
        float p = qc * kv;
        p += __shfl_xor(p, 1);
        p += __shfl_xor(p, 2);
        p += __shfl_xor(p, 4);
        p += __shfl_xor(p, 8);
        p += __shfl_xor(p, 16);        // per-head (32-lane) dot product
        float w = expf(p);             // p_rel/sqrt(D) already folded into kr
        den += w;
        acc += w * vv;
    }
    if (den > 0.f) agg[(size_t)d * CH + c] += acc / den;
}

// ---------------- orchestration ----------------
extern "C" void kernel_launch(void* const* d_in, const int* in_sizes, int n_in,
                              void* d_out, int out_size, void* d_ws, size_t ws_size,
                              hipStream_t stream)
{
    const float* x_user = (const float*)d_in[0];
    const float* x_news = (const float*)d_in[1];
    const int* ei0 = (const int*)d_in[2];   // posts: user -> news
    const int* ei1 = (const int*)d_in[3];   // rev:   news -> user
    const int* ei2 = (const int*)d_in[4];   // follows: user -> user
    const float* Wk = (const float*)d_in[5];
    const float* bk = (const float*)d_in[6];
    const float* Wq = (const float*)d_in[7];
    const float* bq = (const float*)d_in[8];
    const float* Wv = (const float*)d_in[9];
    const float* bv = (const float*)d_in[10];
    const float* Wa = (const float*)d_in[11];
    const float* ba = (const float*)d_in[12];
    const float* skip = (const float*)d_in[13];
    const float* a_rel = (const float*)d_in[14];
    const float* m_rel = (const float*)d_in[15];
    const float* p_rel = (const float*)d_in[16];

    float* ws = (float*)d_ws;
    float* q_user   = ws + OFF_QU;
    float* q_news   = ws + OFF_QN;
    float* agg_user = ws + OFF_AGU;
    float* agg_news = ws + OFF_AGN;
    float* wke = ws + OFF_WKE;
    float* bke = ws + OFF_BKE;
    float* wve = ws + OFF_WVE;
    float* bve = ws + OFF_BVE;
    __half* kr_buf = (__half*)(ws + OFF_KRH);
    __half* vr_buf = (__half*)(ws + OFF_VRH);
    int* ib = (int*)(ws + OFF_INT);
    int* rp0 = ib + IO_RP0;  int* rp1 = ib + IO_RP1;  int* rp2 = ib + IO_RP2;
    int* cu0 = ib + IO_CUR0; int* cu1 = ib + IO_CUR1; int* cu2 = ib + IO_CUR2;
    int* cl0 = ib + IO_COL0; int* cl1 = ib + IO_COL1; int* cl2 = ib + IO_COL2;

    // ---- CSR build (edge lists are layer-invariant: build once per launch) ----
    {
        int ncur = NNEWS + NUSER + NUSER;
        zero_i_kernel<<<(ncur + 255) / 256, 256, 0, stream>>>(cu0, ncur);
    }
    int g3e = (3 * NE + 255) / 256;
    hist3_kernel<<<g3e, 256, 0, stream>>>(ei0, ei1, ei2, cu0, cu1, cu2);
    scan3_kernel<<<3, 1024, 0, stream>>>(cu0, cu1, cu2, rp0, rp1, rp2);
    fill3_kernel<<<g3e, 256, 0, stream>>>(ei0, ei1, ei2, cu0, cu1, cu2, cl0, cl1, cl2);

    auto gemm = [&](const float* A, const float* Wm, const float* bi, void* out, int N,
                    int gin, int dskip, int ohalf, const float* sv, const float* xo) {
        gemm128_kernel<<<(N + 63) / 64, 256, 0, stream>>>(A, Wm, bi, (float*)out, N,
                                                          gin, dskip, ohalf, sv, xo);
    };

    float* out_user = (float*)d_out;                         // layer outputs live in d_out
    float* out_news = (float*)d_out + (size_t)NUSER * CH;    // (layer 1 updates in-place)

    for (int l = 0; l < 2; ++l) {
        const float* xu = l ? (const float*)out_user : x_user;
        const float* xn = l ? (const float*)out_news : x_news;

        eff_weights_kernel<<<6, 256, 0, stream>>>(
            Wk + (size_t)l * 2 * 16384, bk + (size_t)l * 2 * 128,
            Wv + (size_t)l * 2 * 16384, bv + (size_t)l * 2 * 128,
            a_rel + (size_t)l * 3 * 4096, m_rel + (size_t)l * 3 * 4096,
            p_rel + (size_t)l * 12, wke, bke, wve, bve);

        gemm(xu, Wq + (size_t)(l * 2 + 0) * 16384, bq + (size_t)(l * 2 + 0) * 128,
             q_user, NUSER, 0, 0, 0, nullptr, nullptr);
        gemm(xn, Wq + (size_t)(l * 2 + 1) * 16384, bq + (size_t)(l * 2 + 1) * 128,
             q_news, NNEWS, 0, 0, 0, nullptr, nullptr);

        {
            int n4 = (NUSER + NNEWS) * CH / 4;
            zero_f4_kernel<<<(n4 + 255) / 256, 256, 0, stream>>>((float4*)agg_user, n4);
        }

        // relation 0: user -> news
        gemm(xu, wke + 0 * 16384, bke + 0 * 128, kr_buf, NUSER, 0, 0, 1, nullptr, nullptr);
        gemm(xu, wve + 0 * 16384, bve + 0 * 128, vr_buf, NUSER, 0, 0, 1, nullptr, nullptr);
        attn_kernel<<<(NNEWS + 1) / 2, 256, 0, stream>>>(q_news, kr_buf, vr_buf, rp0, cl0,
                                                         agg_news, NNEWS);
        // relation 1: news -> user
        gemm(xn, wke + 1 * 16384, bke + 1 * 128, kr_buf, NNEWS, 0, 0, 1, nullptr, nullptr);
        gemm(xn, wve + 1 * 16384, bve + 1 * 128, vr_buf, NNEWS, 0, 0, 1, nullptr, nullptr);
        attn_kernel<<<(NUSER + 1) / 2, 256, 0, stream>>>(q_user, kr_buf, vr_buf, rp1, cl1,
                                                         agg_user, NUSER);
        // relation 2: user -> user
        gemm(xu, wke + 2 * 16384, bke + 2 * 128, kr_buf, NUSER, 0, 0, 1, nullptr, nullptr);
        gemm(xu, wve + 2 * 16384, bve + 2 * 128, vr_buf, NUSER, 0, 0, 1, nullptr, nullptr);
        attn_kernel<<<(NUSER + 1) / 2, 256, 0, stream>>>(q_user, kr_buf, vr_buf, rp2, cl2,
                                                         agg_user, NUSER);

        // output transform: relu(sig(skip)*(gelu(agg)@Wa + ba) + (1-sig)*x)  [in-place safe]
        gemm(agg_user, Wa + (size_t)(l * 2 + 0) * 16384, ba + (size_t)(l * 2 + 0) * 128,
             out_user, NUSER, 1, 1, 0, skip + l * 2 + 0, xu);
        gemm(agg_news, Wa + (size_t)(l * 2 + 1) * 16384, ba + (size_t)(l * 2 + 1) * 128,
             out_news, NNEWS, 1, 1, 0, skip + l * 2 + 1, xn);
    }
    (void)in_sizes; (void)n_in; (void)out_size; (void)ws_size;
}

// Round 3
// 1297.628 us; speedup vs baseline: 1.4335x; 1.4335x over previous
//
#include <hip/hip_runtime.h>
#include <cmath>

// ---------------- problem constants ----------------
constexpr int NUSER = 100000;
constexpr int NNEWS = 20000;
constexpr int CH    = 128;
constexpr int NE    = 250000;

typedef _Float16 f16x8 __attribute__((ext_vector_type(8)));
typedef _Float16 f16x4 __attribute__((ext_vector_type(4)));
typedef _Float16 f16x2 __attribute__((ext_vector_type(2)));
typedef float    f32x4 __attribute__((ext_vector_type(4)));

// ---------------- workspace layout (float units) ----------------
constexpr size_t OFF_QU  = 0;                                   // q_user  fp16 [NUSER*128]
constexpr size_t OFF_QN  = OFF_QU  + (size_t)NUSER * CH / 2;    // q_news  fp16
constexpr size_t OFF_AGU = OFF_QN  + (size_t)NNEWS * CH / 2;    // agg_user f32
constexpr size_t OFF_AGN = OFF_AGU + (size_t)NUSER * CH;        // agg_news f32
constexpr size_t OFF_KB  = OFF_AGN + (size_t)NNEWS * CH;        // kr big (user src) fp16
constexpr size_t OFF_VB  = OFF_KB  + (size_t)NUSER * CH / 2;    // vr big fp16
constexpr size_t OFF_KS  = OFF_VB  + (size_t)NUSER * CH / 2;    // kr small (news src) fp16
constexpr size_t OFF_VS  = OFF_KS  + (size_t)NNEWS * CH / 2;    // vr small fp16
constexpr size_t OFF_WT  = OFF_VS  + (size_t)NNEWS * CH / 2;    // fp16 weights: wkt[3]+wvt[3]+wqt[2]+wat[2] = 10*8192 floats
constexpr size_t OFF_BE  = OFF_WT  + 10 * 8192;                 // bke[3*128] + bve[3*128] f32
constexpr size_t OFF_INT = OFF_BE  + 6 * 128;                   // int region
constexpr size_t IO_RP0  = 0;
constexpr size_t IO_RP1  = IO_RP0 + (NNEWS + 1);
constexpr size_t IO_RP2  = IO_RP1 + (NUSER + 1);
constexpr size_t IO_CUR0 = IO_RP2 + (NUSER + 1);
constexpr size_t IO_CUR1 = IO_CUR0 + NNEWS;
constexpr size_t IO_CUR2 = IO_CUR1 + NUSER;
constexpr size_t IO_COL0 = IO_CUR2 + NUSER;
constexpr size_t IO_COL1 = IO_COL0 + NE;
constexpr size_t IO_COL2 = IO_COL1 + NE;

__device__ __forceinline__ float gelu_f(float x) {
    return 0.5f * x * (1.0f + erff(x * 0.70710678118654752440f));
}

__global__ void zero_i_kernel(int* __restrict__ p, int n) {
    int i = blockIdx.x * 256 + threadIdx.x;
    if (i < n) p[i] = 0;
}

// ---------------- CSR build ----------------
__global__ void hist3_kernel(const int* __restrict__ e0, const int* __restrict__ e1,
                             const int* __restrict__ e2,
                             int* __restrict__ c0, int* __restrict__ c1, int* __restrict__ c2) {
    int idx = blockIdx.x * 256 + threadIdx.x;
    if (idx >= 3 * NE) return;
    int r = idx / NE, e = idx - r * NE;
    const int* ei = (r == 0) ? e0 : (r == 1) ? e1 : e2;
    int*       cu = (r == 0) ? c0 : (r == 1) ? c1 : c2;
    atomicAdd(&cu[ei[NE + e]], 1);
}

__global__ __launch_bounds__(1024) void scan3_kernel(int* __restrict__ c0, int* __restrict__ c1,
                                                     int* __restrict__ c2, int* __restrict__ r0,
                                                     int* __restrict__ r1, int* __restrict__ r2) {
    __shared__ int swave[16];
    int rsel = blockIdx.x;
    int* cur = (rsel == 0) ? c0 : (rsel == 1) ? c1 : c2;
    int* rp  = (rsel == 0) ? r0 : (rsel == 1) ? r1 : r2;
    int n    = (rsel == 0) ? NNEWS : NUSER;
    int tid = threadIdx.x, lane = tid & 63, w = tid >> 6;
    int base = 0;
    for (int start = 0; start < n; start += 1024) {
        int i = start + tid;
        int v = (i < n) ? cur[i] : 0;
        int x = v;
        #pragma unroll
        for (int off = 1; off < 64; off <<= 1) {
            int y = __shfl_up(x, off);
            if (lane >= off) x += y;
        }
        if (lane == 63) swave[w] = x;
        __syncthreads();
        if (tid < 16) {
            int t = swave[tid];
            #pragma unroll
            for (int off = 1; off < 16; off <<= 1) {
                int y = __shfl_up(t, off);
                if (tid >= off) t += y;
            }
            swave[tid] = t;
        }
        __syncthreads();
        int woff = (w > 0) ? swave[w - 1] : 0;
        int excl = base + woff + x - v;
        if (i < n) { rp[i] = excl; cur[i] = excl; }
        base += swave[15];
        __syncthreads();
    }
    if (tid == 0) rp[n] = base;
}

__global__ void fill3_kernel(const int* __restrict__ e0, const int* __restrict__ e1,
                             const int* __restrict__ e2,
                             int* __restrict__ c0, int* __restrict__ c1, int* __restrict__ c2,
                             int* __restrict__ l0, int* __restrict__ l1, int* __restrict__ l2) {
    int idx = blockIdx.x * 256 + threadIdx.x;
    if (idx >= 3 * NE) return;
    int r = idx / NE, e = idx - r * NE;
    const int* ei = (r == 0) ? e0 : (r == 1) ? e1 : e2;
    int*       cu = (r == 0) ? c0 : (r == 1) ? c1 : c2;
    int*       cl = (r == 0) ? l0 : (r == 1) ? l1 : l2;
    int dst = ei[NE + e], src = ei[e];
    int p = atomicAdd(&cu[dst], 1);
    cl[p] = src;
}

// ---------------- effective weights (fp16, TRANSPOSED: Wt[col][k]) ----------------
__global__ void eff_weights_kernel(const float* __restrict__ Wk, const float* __restrict__ bk,
                                   const float* __restrict__ Wv, const float* __restrict__ bv,
                                   const float* __restrict__ a_rel, const float* __restrict__ m_rel,
                                   const float* __restrict__ p_rel,
                                   _Float16* __restrict__ wkt, float* __restrict__ bke,
                                   _Float16* __restrict__ wvt, float* __restrict__ bve) {
    int b = blockIdx.x;         // 0..5
    int kind = b / 3;           // 0 = K, 1 = V
    int r = b % 3;
    const int st = (r == 1) ? 1 : 0;
    const float* W   = (kind ? Wv : Wk) + (size_t)st * 16384;
    const float* bi  = (kind ? bv : bk) + (size_t)st * 128;
    const float* rel = (kind ? m_rel : a_rel) + (size_t)r * 4096;
    _Float16* Wt = (kind ? wvt : wkt) + (size_t)r * 16384;
    float*    be = (kind ? bve : bke) + (size_t)r * 128;
    const float invsq = 0.17677669529663688f;   // 1/sqrt(32)
    for (int o = threadIdx.x; o < 16384; o += 256) {
        int c = o >> 7, col = o & 127, h = col >> 5, e = col & 31;
        const float* wrow = W + (size_t)c * 128 + h * 32;
        const float* rcol = rel + h * 1024 + e;
        float s = 0.f;
        #pragma unroll
        for (int d = 0; d < 32; ++d) s += wrow[d] * rcol[d * 32];
        if (kind == 0) s *= p_rel[r * 4 + h] * invsq;
        Wt[(size_t)col * 128 + c] = (_Float16)s;     // transposed store
    }
    if (threadIdx.x < 128) {
        int col = threadIdx.x, h = col >> 5, e = col & 31;
        float s = 0.f;
        #pragma unroll
        for (int d = 0; d < 32; ++d) s += bi[h * 32 + d] * rel[h * 1024 + d * 32 + e];
        if (kind == 0) s *= p_rel[r * 4 + h] * invsq;
        be[col] = s;
    }
}

// Wq / Wa -> fp16 transposed
__global__ void wt_convert_kernel(const float* __restrict__ Wq, const float* __restrict__ Wa,
                                  _Float16* __restrict__ wqt, _Float16* __restrict__ wat) {
    int b = blockIdx.x;  // 0,1: Wq types; 2,3: Wa types
    const float* W  = (b < 2) ? (Wq + (size_t)b * 16384) : (Wa + (size_t)(b - 2) * 16384);
    _Float16*   Wt = (b < 2) ? (wqt + (size_t)b * 16384) : (wat + (size_t)(b - 2) * 16384);
    for (int o = threadIdx.x; o < 16384; o += 256) {
        int k = o >> 7, col = o & 127;
        Wt[(size_t)col * 128 + k] = (_Float16)W[o];
    }
}

// ---------------- MFMA GEMM: out[n,col] = epi(sum_k A[n,k]*Wt[col,k] + bias[col]) ----------------
// A fp32 [N,128] (fp16-converted on stage), Wt fp16 [128,128] transposed.
// 256 threads = 4 waves, 64 rows x 128 cols per block. v_mfma_f32_16x16x32_f16.
__global__ __launch_bounds__(256) void mfma_gemm_kernel(
    const float* __restrict__ A, const _Float16* __restrict__ Wt,
    const float* __restrict__ bias, void* __restrict__ Cout, int N,
    int gelu_in, int do_skip, int out_half, const float* __restrict__ skipv,
    const float* __restrict__ Xold)
{
    constexpr int LS = 136;               // halves; 272B row: 16B aligned, 2-way banks (free)
    __shared__ _Float16 sA[64 * LS];      // 17.4 KB
    __shared__ _Float16 sW[128 * LS];     // 34.8 KB
    const int tid  = threadIdx.x;
    const int row0 = blockIdx.x * 64;

    // stage A (fp32 -> fp16), 64x128: 2048 float4-chunks / 256 threads
    for (int i = tid; i < 64 * 32; i += 256) {
        int r = i >> 5, q = i & 31;
        int gr = row0 + r;
        float4 v = make_float4(0.f, 0.f, 0.f, 0.f);
        if (gr < N) v = *(const float4*)(A + (size_t)gr * CH + q * 4);
        if (gelu_in) { v.x = gelu_f(v.x); v.y = gelu_f(v.y); v.z = gelu_f(v.z); v.w = gelu_f(v.w); }
        f16x4 h = { (_Float16)v.x, (_Float16)v.y, (_Float16)v.z, (_Float16)v.w };
        *(f16x4*)(sA + r * LS + q * 4) = h;
    }
    // stage Wt fp16, 128x128: 2048 16B-chunks / 256 threads
    for (int i = tid; i < 128 * 16; i += 256) {
        int c = i >> 4, q = i & 15;
        *(f16x8*)(sW + c * LS + q * 8) = *(const f16x8*)(Wt + (size_t)c * 128 + q * 8);
    }
    __syncthreads();

    const int wave = tid >> 6, lane = tid & 63;
    const int m = lane & 15, quad = lane >> 4;
    const int arow = wave * 16 + m;

    f32x4 acc[8];
    #pragma unroll
    for (int t = 0; t < 8; ++t) acc[t] = (f32x4){0.f, 0.f, 0.f, 0.f};

    #pragma unroll
    for (int kt = 0; kt < 4; ++kt) {
        // A-frag: A[m=lane&15][k=quad*8+j]
        f16x8 af = *(const f16x8*)(sA + arow * LS + kt * 32 + quad * 8);
        #pragma unroll
        for (int ct = 0; ct < 8; ++ct) {
            // B-frag: B[k=quad*8+j][n=lane&15] == Wt[col][k]
            f16x8 bf = *(const f16x8*)(sW + (ct * 16 + m) * LS + kt * 32 + quad * 8);
            acc[ct] = __builtin_amdgcn_mfma_f32_16x16x32_f16(af, bf, acc[ct], 0, 0, 0);
        }
    }

    // epilogue: C/D layout col=lane&15, row=quad*4+reg
    float aS = 0.f, bS = 0.f;
    if (do_skip) {
        float sv = skipv[0];
        aS = 1.0f / (1.0f + expf(-sv));
        bS = 1.0f - aS;
    }
    #pragma unroll
    for (int ct = 0; ct < 8; ++ct) {
        int gcol = ct * 16 + m;
        float bb = bias[gcol];
        #pragma unroll
        for (int rg = 0; rg < 4; ++rg) {
            int grow = row0 + wave * 16 + quad * 4 + rg;
            if (grow >= N) continue;
            float o = acc[ct][rg] + bb;
            if (do_skip) {
                float xo = Xold[(size_t)grow * CH + gcol];
                o = fmaxf(aS * o + bS * xo, 0.f);
            }
            if (out_half) ((_Float16*)Cout)[(size_t)grow * CH + gcol] = (_Float16)o;
            else          ((float*)Cout)[(size_t)grow * CH + gcol] = o;
        }
    }
}

// ---------------- attention: one 64-lane wave per dst node, half2 per lane ----------------
// Processes 1 or 2 relations (separately-normalized softmax each), ASSIGNS agg (no RMW).
__global__ __launch_bounds__(256) void attn_kernel(
    const _Float16* __restrict__ q,
    const _Float16* __restrict__ k1, const _Float16* __restrict__ v1,
    const int* __restrict__ rp1, const int* __restrict__ cl1,
    const _Float16* __restrict__ k2, const _Float16* __restrict__ v2,
    const int* __restrict__ rp2, const int* __restrict__ cl2,
    float* __restrict__ agg, int Ndst, int two)
{
    int d = blockIdx.x * 4 + (threadIdx.x >> 6);
    if (d >= Ndst) return;
    int c2 = threadIdx.x & 63;                 // channel pair; head = c2>>4
    f16x2 qv = *(const f16x2*)(q + (size_t)d * CH + c2 * 2);
    float qx = (float)qv[0], qy = (float)qv[1];
    float ax = 0.f, ay = 0.f;
    for (int rel = 0; rel < 1 + two; ++rel) {
        const _Float16* kr = rel ? k2 : k1;
        const _Float16* vr = rel ? v2 : v1;
        const int* rp = rel ? rp2 : rp1;
        const int* cl = rel ? cl2 : cl1;
        int e0 = rp[d], e1 = rp[d + 1];
        float den = 0.f, sx = 0.f, sy = 0.f;
        for (int e = e0; e < e1; ++e) {
            int s = cl[e];
            f16x2 kv = *(const f16x2*)(kr + (size_t)s * CH + c2 * 2);
            f16x2 vv = *(const f16x2*)(vr + (size_t)s * CH + c2 * 2);
            float p = qx * (float)kv[0] + qy * (float)kv[1];
            p += __shfl_xor(p, 1);
            p += __shfl_xor(p, 2);
            p += __shfl_xor(p, 4);
            p += __shfl_xor(p, 8);             // 16-lane (per-head) reduction
            float w = expf(p);                 // p_rel/sqrt(D) folded into k
            den += w;
            sx += w * (float)vv[0];
            sy += w * (float)vv[1];
        }
        if (den > 0.f) { ax += sx / den; ay += sy / den; }
    }
    *(float2*)(agg + (size_t)d * CH + c2 * 2) = make_float2(ax, ay);
}

// ---------------- orchestration ----------------
extern "C" void kernel_launch(void* const* d_in, const int* in_sizes, int n_in,
                              void* d_out, int out_size, void* d_ws, size_t ws_size,
                              hipStream_t stream)
{
    const float* x_user = (const float*)d_in[0];
    const float* x_news = (const float*)d_in[1];
    const int* ei0 = (const int*)d_in[2];
    const int* ei1 = (const int*)d_in[3];
    const int* ei2 = (const int*)d_in[4];
    const float* Wk = (const float*)d_in[5];
    const float* bk = (const float*)d_in[6];
    const float* Wq = (const float*)d_in[7];
    const float* bq = (const float*)d_in[8];
    const float* Wv = (const float*)d_in[9];
    const float* bv = (const float*)d_in[10];
    const float* Wa = (const float*)d_in[11];
    const float* ba = (const float*)d_in[12];
    const float* skip = (const float*)d_in[13];
    const float* a_rel = (const float*)d_in[14];
    const float* m_rel = (const float*)d_in[15];
    const float* p_rel = (const float*)d_in[16];

    float* ws = (float*)d_ws;
    _Float16* q_user  = (_Float16*)(ws + OFF_QU);
    _Float16* q_news  = (_Float16*)(ws + OFF_QN);
    float* agg_user   = ws + OFF_AGU;
    float* agg_news   = ws + OFF_AGN;
    _Float16* kr_big  = (_Float16*)(ws + OFF_KB);
    _Float16* vr_big  = (_Float16*)(ws + OFF_VB);
    _Float16* kr_sm   = (_Float16*)(ws + OFF_KS);
    _Float16* vr_sm   = (_Float16*)(ws + OFF_VS);
    _Float16* wkt = (_Float16*)(ws + OFF_WT);          // 3*16384 halves
    _Float16* wvt = wkt + 3 * 16384;
    _Float16* wqt = wvt + 3 * 16384;
    _Float16* wat = wqt + 2 * 16384;
    float* bke = ws + OFF_BE;
    float* bve = bke + 3 * 128;
    int* ib = (int*)(ws + OFF_INT);
    int* rp0 = ib + IO_RP0;  int* rp1 = ib + IO_RP1;  int* rp2 = ib + IO_RP2;
    int* cu0 = ib + IO_CUR0; int* cu1 = ib + IO_CUR1; int* cu2 = ib + IO_CUR2;
    int* cl0 = ib + IO_COL0; int* cl1 = ib + IO_COL1; int* cl2 = ib + IO_COL2;

    // ---- CSR build ----
    {
        int ncur = NNEWS + NUSER + NUSER;
        zero_i_kernel<<<(ncur + 255) / 256, 256, 0, stream>>>(cu0, ncur);
    }
    int g3e = (3 * NE + 255) / 256;
    hist3_kernel<<<g3e, 256, 0, stream>>>(ei0, ei1, ei2, cu0, cu1, cu2);
    scan3_kernel<<<3, 1024, 0, stream>>>(cu0, cu1, cu2, rp0, rp1, rp2);
    fill3_kernel<<<g3e, 256, 0, stream>>>(ei0, ei1, ei2, cu0, cu1, cu2, cl0, cl1, cl2);

    auto gemm = [&](const float* A, const _Float16* Wt, const float* bi, void* out, int N,
                    int gin, int dskip, int ohalf, const float* sv, const float* xo) {
        mfma_gemm_kernel<<<(N + 63) / 64, 256, 0, stream>>>(A, Wt, bi, out, N,
                                                            gin, dskip, ohalf, sv, xo);
    };

    float* out_user = (float*)d_out;
    float* out_news = (float*)d_out + (size_t)NUSER * CH;

    for (int l = 0; l < 2; ++l) {
        const float* xu = l ? (const float*)out_user : x_user;
        const float* xn = l ? (const float*)out_news : x_news;

        eff_weights_kernel<<<6, 256, 0, stream>>>(
            Wk + (size_t)l * 2 * 16384, bk + (size_t)l * 2 * 128,
            Wv + (size_t)l * 2 * 16384, bv + (size_t)l * 2 * 128,
            a_rel + (size_t)l * 3 * 4096, m_rel + (size_t)l * 3 * 4096,
            p_rel + (size_t)l * 12, wkt, bke, wvt, bve);
        wt_convert_kernel<<<4, 256, 0, stream>>>(Wq + (size_t)l * 2 * 16384,
                                                 Wa + (size_t)l * 2 * 16384, wqt, wat);

        // q projections (fp16 out)
        gemm(xu, wqt,         bq + (size_t)(l * 2 + 0) * 128, q_user, NUSER, 0, 0, 1, nullptr, nullptr);
        gemm(xn, wqt + 16384, bq + (size_t)(l * 2 + 1) * 128, q_news, NNEWS, 0, 0, 1, nullptr, nullptr);

        // relation 0: user -> news
        gemm(xu, wkt,         bke,       kr_big, NUSER, 0, 0, 1, nullptr, nullptr);
        gemm(xu, wvt,         bve,       vr_big, NUSER, 0, 0, 1, nullptr, nullptr);
        attn_kernel<<<(NNEWS + 3) / 4, 256, 0, stream>>>(
            q_news, kr_big, vr_big, rp0, cl0,
            nullptr, nullptr, nullptr, nullptr, agg_news, NNEWS, 0);

        // relations 1 (news->user) + 2 (user->user), fused dst pass
        gemm(xn, wkt + 16384, bke + 128, kr_sm,  NNEWS, 0, 0, 1, nullptr, nullptr);
        gemm(xn, wvt + 16384, bve + 128, vr_sm,  NNEWS, 0, 0, 1, nullptr, nullptr);
        gemm(xu, wkt + 32768, bke + 256, kr_big, NUSER, 0, 0, 1, nullptr, nullptr);
        gemm(xu, wvt + 32768, bve + 256, vr_big, NUSER, 0, 0, 1, nullptr, nullptr);
        attn_kernel<<<(NUSER + 3) / 4, 256, 0, stream>>>(
            q_user, kr_sm, vr_sm, rp1, cl1,
            kr_big, vr_big, rp2, cl2, agg_user, NUSER, 1);

        // output transform: relu(sig(skip)*(gelu(agg)@Wa + ba) + (1-sig)*x)  [in-place safe]
        gemm(agg_user, wat,         ba + (size_t)(l * 2 + 0) * 128, out_user, NUSER, 1, 1, 0,
             skip + l * 2 + 0, xu);
        gemm(agg_news, wat + 16384, ba + (size_t)(l * 2 + 1) * 128, out_news, NNEWS, 1, 1, 0,
             skip + l * 2 + 1, xn);
    }
    (void)in_sizes; (void)n_in; (void)out_size; (void)ws_size;
}

// Round 4
// 997.028 us; speedup vs baseline: 1.8657x; 1.3015x over previous
//
#include <hip/hip_runtime.h>
#include <cmath>

// ---------------- problem constants ----------------
constexpr int NUSER = 100000;
constexpr int NNEWS = 20000;
constexpr int CH    = 128;
constexpr int NE    = 250000;
constexpr int NTOT  = NNEWS + NUSER + NUSER;   // joint counter array (rel0|rel1|rel2)
constexpr int NSB   = (NTOT + 255) / 256;      // scan blocks = 860

typedef _Float16 f16x8 __attribute__((ext_vector_type(8)));
typedef _Float16 f16x4 __attribute__((ext_vector_type(4)));
typedef float    f32x4 __attribute__((ext_vector_type(4)));

// ---------------- workspace layout (float units) ----------------
constexpr size_t OFF_QU  = 0;                                   // q_user fp16 [NUSER*128]
constexpr size_t OFF_QN  = OFF_QU  + (size_t)NUSER * 64;        // q_news fp16
constexpr size_t OFF_AGU = OFF_QN  + (size_t)NNEWS * 64;        // agg_user fp16
constexpr size_t OFF_AGN = OFF_AGU + (size_t)NUSER * 64;        // agg_news fp16
constexpr size_t OFF_KVB = OFF_AGN + (size_t)NNEWS * 64;        // kv_big fp16 [NUSER][256] (k|v interleaved)
constexpr size_t OFF_KVS = OFF_KVB + (size_t)NUSER * 128;       // kv_sm  fp16 [NNEWS][256]
constexpr size_t OFF_WF  = OFF_KVS + (size_t)NNEWS * 128;       // swizzled fp16 frags: wk[3],wv[3],wq[2],wa[2] = 10*8192 floats
constexpr size_t OFF_BE  = OFF_WF  + 10 * 8192;                 // bke[3*128]+bve[3*128] f32
constexpr size_t OFF_INT = OFF_BE  + 6 * 128;
// int offsets (relative, units: int)
constexpr size_t IO_CU   = 0;                    // joint counters/cursors [NTOT]
constexpr size_t IO_JRP  = IO_CU  + NTOT;        // joint row_ptr [NTOT+1]
constexpr size_t IO_BSUM = IO_JRP + NTOT + 1;    // scan partials [NSB]
constexpr size_t IO_BOFF = IO_BSUM + NSB;        // scan offsets  [NSB]
constexpr size_t IO_CL   = IO_BOFF + NSB;        // col (global slots) [3*NE]

__device__ __forceinline__ float gelu_f(float x) {
    return 0.5f * x * (1.0f + erff(x * 0.70710678118654752440f));
}

__global__ void zero_i_kernel(int* __restrict__ p, int n) {
    int i = blockIdx.x * 256 + threadIdx.x;
    if (i < n) p[i] = 0;
}

// ---------------- CSR build (joint counter array) ----------------
__global__ void hist3_kernel(const int* __restrict__ e0, const int* __restrict__ e1,
                             const int* __restrict__ e2, int* __restrict__ cu) {
    int idx = blockIdx.x * 256 + threadIdx.x;
    if (idx >= 3 * NE) return;
    int r = idx / NE, e = idx - r * NE;
    const int* ei = (r == 0) ? e0 : (r == 1) ? e1 : e2;
    int base = (r == 0) ? 0 : (r == 1) ? NNEWS : (NNEWS + NUSER);
    atomicAdd(&cu[base + ei[NE + e]], 1);
}

__global__ __launch_bounds__(256) void scan_part_kernel(const int* __restrict__ cu,
                                                        int* __restrict__ bsum) {
    int i = blockIdx.x * 256 + threadIdx.x;
    int v = (i < NTOT) ? cu[i] : 0;
    #pragma unroll
    for (int o = 1; o < 64; o <<= 1) v += __shfl_xor(v, o);
    __shared__ int ws_[4];
    if ((threadIdx.x & 63) == 0) ws_[threadIdx.x >> 6] = v;
    __syncthreads();
    if (threadIdx.x == 0) bsum[blockIdx.x] = ws_[0] + ws_[1] + ws_[2] + ws_[3];
}

__global__ __launch_bounds__(1024) void scan_top_kernel(const int* __restrict__ bsum,
                                                        int* __restrict__ boff,
                                                        int* __restrict__ jrp) {
    __shared__ int wsum[16];
    int tid = threadIdx.x, lane = tid & 63, w = tid >> 6;
    int v = (tid < NSB) ? bsum[tid] : 0;
    int x = v;
    #pragma unroll
    for (int o = 1; o < 64; o <<= 1) { int y = __shfl_up(x, o); if (lane >= o) x += y; }
    if (lane == 63) wsum[w] = x;
    __syncthreads();
    if (tid < 16) {
        int t = wsum[tid];
        #pragma unroll
        for (int o = 1; o < 16; o <<= 1) { int y = __shfl_up(t, o); if (tid >= o) t += y; }
        wsum[tid] = t;
    }
    __syncthreads();
    int woff = w ? wsum[w - 1] : 0;
    if (tid < NSB) boff[tid] = woff + x - v;
    if (tid == 0) jrp[NTOT] = 3 * NE;
}

__global__ __launch_bounds__(256) void scan_fin_kernel(const int* __restrict__ cu,
                                                       const int* __restrict__ boff,
                                                       int* __restrict__ jrp,
                                                       int* __restrict__ cur) {
    __shared__ int wsum[4];
    int tid = threadIdx.x, lane = tid & 63, w = tid >> 6;
    int i = blockIdx.x * 256 + tid;
    int v = (i < NTOT) ? cu[i] : 0;
    int x = v;
    #pragma unroll
    for (int o = 1; o < 64; o <<= 1) { int y = __shfl_up(x, o); if (lane >= o) x += y; }
    if (lane == 63) wsum[w] = x;
    __syncthreads();
    int woff = 0;
    #pragma unroll
    for (int k = 0; k < 4; ++k) if (k < w) woff += wsum[k];
    int excl = boff[blockIdx.x] + woff + x - v;
    if (i < NTOT) { jrp[i] = excl; cur[i] = excl; }
}

__global__ void fill3_kernel(const int* __restrict__ e0, const int* __restrict__ e1,
                             const int* __restrict__ e2,
                             int* __restrict__ cur, int* __restrict__ cl) {
    int idx = blockIdx.x * 256 + threadIdx.x;
    if (idx >= 3 * NE) return;
    int r = idx / NE, e = idx - r * NE;
    const int* ei = (r == 0) ? e0 : (r == 1) ? e1 : e2;
    int base = (r == 0) ? 0 : (r == 1) ? NNEWS : (NNEWS + NUSER);
    int dst = ei[NE + e], src = ei[e];
    int p = atomicAdd(&cur[base + dst], 1);
    cl[p] = src;
}

// ---------------- swizzled-fragment dest index ----------------
// MFMA 16x16x32 fragment (lane,j): idx = lane&15, k = (lane>>4)*8 + j.
// Wf layout: [kt][ct][lane][j] contiguous -> wave reads b128/lane, fully coalesced.
__device__ __forceinline__ int frag_dest(int k, int col) {
    int kt = k >> 5, quad = (k >> 3) & 3, j = k & 7;
    int ct = col >> 4, m = col & 15;
    int lane = quad * 16 + m;
    return ((kt * 8 + ct) * 64 + lane) * 8 + j;
}

// ---------------- effective weights (fold a_rel/m_rel/p_rel), swizzled fp16 ----------------
__global__ void eff_weights_kernel(const float* __restrict__ Wk, const float* __restrict__ bk,
                                   const float* __restrict__ Wv, const float* __restrict__ bv,
                                   const float* __restrict__ a_rel, const float* __restrict__ m_rel,
                                   const float* __restrict__ p_rel,
                                   _Float16* __restrict__ wkf, float* __restrict__ bke,
                                   _Float16* __restrict__ wvf, float* __restrict__ bve) {
    int b = blockIdx.x;         // 0..5
    int kind = b / 3;           // 0 = K, 1 = V
    int r = b % 3;
    const int st = (r == 1) ? 1 : 0;
    const float* W   = (kind ? Wv : Wk) + (size_t)st * 16384;
    const float* bi  = (kind ? bv : bk) + (size_t)st * 128;
    const float* rel = (kind ? m_rel : a_rel) + (size_t)r * 4096;
    _Float16* Wf = (kind ? wvf : wkf) + (size_t)r * 16384;
    float*    be = (kind ? bve : bke) + (size_t)r * 128;
    const float invsq = 0.17677669529663688f;   // 1/sqrt(32)
    for (int o = threadIdx.x; o < 16384; o += 256) {
        int k = o >> 7, col = o & 127, h = col >> 5, e = col & 31;
        const float* wrow = W + (size_t)k * 128 + h * 32;
        const float* rcol = rel + h * 1024 + e;
        float s = 0.f;
        #pragma unroll
        for (int d = 0; d < 32; ++d) s += wrow[d] * rcol[d * 32];
        if (kind == 0) s *= p_rel[r * 4 + h] * invsq;
        Wf[frag_dest(k, col)] = (_Float16)s;
    }
    if (threadIdx.x < 128) {
        int col = threadIdx.x, h = col >> 5, e = col & 31;
        float s = 0.f;
        #pragma unroll
        for (int d = 0; d < 32; ++d) s += bi[h * 32 + d] * rel[h * 1024 + d * 32 + e];
        if (kind == 0) s *= p_rel[r * 4 + h] * invsq;
        be[col] = s;
    }
}

__global__ void wt_convert_kernel(const float* __restrict__ Wq, const float* __restrict__ Wa,
                                  _Float16* __restrict__ wqf, _Float16* __restrict__ waf) {
    int b = blockIdx.x;  // 0,1: Wq types; 2,3: Wa types
    const float* W  = (b < 2) ? (Wq + (size_t)b * 16384) : (Wa + (size_t)(b - 2) * 16384);
    _Float16*   Wf = (b < 2) ? (wqf + (size_t)b * 16384) : (waf + (size_t)(b - 2) * 16384);
    for (int o = threadIdx.x; o < 16384; o += 256) {
        int k = o >> 7, col = o & 127;
        Wf[frag_dest(k, col)] = (_Float16)W[o];
    }
}

// ---------------- LDS-free MFMA GEMM, up to 2 fused outputs ----------------
// Each wave: 16 nodes x 128 out-ch. mfma(A=Wfrag, B=Xfrag): D col = node (lane&15),
// D rows = out channels (quad*4+reg) -> vectorized x4 stores.
template<int NOUT, bool IN_HALF, bool GELU_IN, bool SKIP_OUT, bool OUT_HALF>
__global__ __launch_bounds__(256) void gemm_v2(
    const void* __restrict__ Ain,
    const _Float16* __restrict__ Wf0, const _Float16* __restrict__ Wf1,
    const float* __restrict__ b0, const float* __restrict__ b1,
    void* __restrict__ out0, void* __restrict__ out1, int ostride,
    int N, const float* __restrict__ skipv, const float* __restrict__ Xold)
{
    int wv = blockIdx.x * 4 + (threadIdx.x >> 6);
    if (wv * 16 >= N) return;
    const int lane = threadIdx.x & 63;
    const int m = lane & 15, quad = lane >> 4;
    const int node = wv * 16 + m;

    f32x4 acc0[8], acc1[8];
    #pragma unroll
    for (int t = 0; t < 8; ++t) {
        acc0[t] = (f32x4){0.f, 0.f, 0.f, 0.f};
        if (NOUT > 1) acc1[t] = (f32x4){0.f, 0.f, 0.f, 0.f};
    }

    #pragma unroll
    for (int kt = 0; kt < 4; ++kt) {
        f16x8 xf;
        if (IN_HALF) {
            xf = *(const f16x8*)((const _Float16*)Ain + (size_t)node * 128 + kt * 32 + quad * 8);
            if (GELU_IN) {
                #pragma unroll
                for (int j = 0; j < 8; ++j) xf[j] = (_Float16)gelu_f((float)xf[j]);
            }
        } else {
            const float* Af = (const float*)Ain + (size_t)node * 128 + kt * 32 + quad * 8;
            f32x4 a0 = *(const f32x4*)Af;
            f32x4 a1 = *(const f32x4*)(Af + 4);
            if (GELU_IN) {
                #pragma unroll
                for (int j = 0; j < 4; ++j) { a0[j] = gelu_f(a0[j]); a1[j] = gelu_f(a1[j]); }
            }
            xf = (f16x8){(_Float16)a0[0], (_Float16)a0[1], (_Float16)a0[2], (_Float16)a0[3],
                         (_Float16)a1[0], (_Float16)a1[1], (_Float16)a1[2], (_Float16)a1[3]};
        }
        #pragma unroll
        for (int ct = 0; ct < 8; ++ct) {
            f16x8 wf0 = *(const f16x8*)(Wf0 + ((size_t)(kt * 8 + ct) * 64 + lane) * 8);
            acc0[ct] = __builtin_amdgcn_mfma_f32_16x16x32_f16(wf0, xf, acc0[ct], 0, 0, 0);
            if (NOUT > 1) {
                f16x8 wf1 = *(const f16x8*)(Wf1 + ((size_t)(kt * 8 + ct) * 64 + lane) * 8);
                acc1[ct] = __builtin_amdgcn_mfma_f32_16x16x32_f16(wf1, xf, acc1[ct], 0, 0, 0);
            }
        }
    }

    float aS = 0.f, bSk = 0.f;
    if (SKIP_OUT) {
        float sv = skipv[0];
        aS = 1.0f / (1.0f + expf(-sv));
        bSk = 1.0f - aS;
    }
    #pragma unroll
    for (int ct = 0; ct < 8; ++ct) {
        int c = ct * 16 + quad * 4;      // out-channel base for this lane's 4 regs
        {
            f32x4 r = acc0[ct] + *(const f32x4*)(b0 + c);
            if (SKIP_OUT) {
                f32x4 xo = *(const f32x4*)(Xold + (size_t)node * 128 + c);
                #pragma unroll
                for (int j = 0; j < 4; ++j) r[j] = fmaxf(aS * r[j] + bSk * xo[j], 0.f);
            }
            if (OUT_HALF) {
                f16x4 h = {(_Float16)r[0], (_Float16)r[1], (_Float16)r[2], (_Float16)r[3]};
                *(f16x4*)((_Float16*)out0 + (size_t)node * ostride + c) = h;
            } else {
                *(f32x4*)((float*)out0 + (size_t)node * ostride + c) = r;
            }
        }
        if (NOUT > 1) {
            f32x4 r = acc1[ct] + *(const f32x4*)(b1 + c);
            f16x4 h = {(_Float16)r[0], (_Float16)r[1], (_Float16)r[2], (_Float16)r[3]};
            *(f16x4*)((_Float16*)out1 + (size_t)node * ostride + c) = h;
        }
    }
}

// ---------------- attention: 1 node/wave, 2 edges/iter (32 lanes x f16x4 each) ----------------
// kv interleaved [node][k0..k127 | v0..v127] fp16 -> one 512B row per edge.
__global__ __launch_bounds__(256) void attn_v2(
    const _Float16* __restrict__ q,
    const _Float16* __restrict__ kv1, const int* __restrict__ rp1,
    const _Float16* __restrict__ kv2, const int* __restrict__ rp2,
    const int* __restrict__ cl,
    _Float16* __restrict__ agg, int Ndst, int two)
{
    int d = blockIdx.x * 4 + (threadIdx.x >> 6);
    if (d >= Ndst) return;
    const int lane = threadIdx.x & 63;
    const int half = lane >> 5;          // which edge of the pair
    const int c4 = lane & 31;            // channels c4*4 .. +3 ; head = c4>>3
    f16x4 qh = *(const f16x4*)(q + (size_t)d * 128 + c4 * 4);
    float q0 = (float)qh[0], q1 = (float)qh[1], q2 = (float)qh[2], q3 = (float)qh[3];
    float a0 = 0.f, a1 = 0.f, a2 = 0.f, a3 = 0.f;
    for (int rel = 0; rel < 1 + two; ++rel) {
        const _Float16* kv = rel ? kv2 : kv1;
        const int* rp = rel ? rp2 : rp1;
        int e0 = rp[d], e1 = rp[d + 1];
        float den = 0.f, s0 = 0.f, s1 = 0.f, s2 = 0.f, s3 = 0.f;
        for (int e = e0; e < e1; e += 2) {
            int el = e + half;
            bool valid = el < e1;
            int s = cl[valid ? el : e];
            const _Float16* row = kv + (size_t)s * 256;
            f16x4 kk = *(const f16x4*)(row + c4 * 4);
            f16x4 vv = *(const f16x4*)(row + 128 + c4 * 4);
            float p = q0 * (float)kk[0] + q1 * (float)kk[1]
                    + q2 * (float)kk[2] + q3 * (float)kk[3];
            p += __shfl_xor(p, 1);
            p += __shfl_xor(p, 2);
            p += __shfl_xor(p, 4);       // 8 lanes per head
            float w = valid ? expf(p) : 0.f;
            den += w;
            s0 += w * (float)vv[0]; s1 += w * (float)vv[1];
            s2 += w * (float)vv[2]; s3 += w * (float)vv[3];
        }
        den += __shfl_xor(den, 32);      // combine edge-halves
        s0 += __shfl_xor(s0, 32); s1 += __shfl_xor(s1, 32);
        s2 += __shfl_xor(s2, 32); s3 += __shfl_xor(s3, 32);
        if (den > 0.f) {
            float inv = 1.f / den;
            a0 += s0 * inv; a1 += s1 * inv; a2 += s2 * inv; a3 += s3 * inv;
        }
    }
    if (half == 0) {
        f16x4 o = {(_Float16)a0, (_Float16)a1, (_Float16)a2, (_Float16)a3};
        *(f16x4*)(agg + (size_t)d * 128 + c4 * 4) = o;
    }
}

// ---------------- orchestration ----------------
extern "C" void kernel_launch(void* const* d_in, const int* in_sizes, int n_in,
                              void* d_out, int out_size, void* d_ws, size_t ws_size,
                              hipStream_t stream)
{
    const float* x_user = (const float*)d_in[0];
    const float* x_news = (const float*)d_in[1];
    const int* ei0 = (const int*)d_in[2];
    const int* ei1 = (const int*)d_in[3];
    const int* ei2 = (const int*)d_in[4];
    const float* Wk = (const float*)d_in[5];
    const float* bk = (const float*)d_in[6];
    const float* Wq = (const float*)d_in[7];
    const float* bq = (const float*)d_in[8];
    const float* Wv = (const float*)d_in[9];
    const float* bv = (const float*)d_in[10];
    const float* Wa = (const float*)d_in[11];
    const float* ba = (const float*)d_in[12];
    const float* skip = (const float*)d_in[13];
    const float* a_rel = (const float*)d_in[14];
    const float* m_rel = (const float*)d_in[15];
    const float* p_rel = (const float*)d_in[16];

    float* ws = (float*)d_ws;
    _Float16* q_user  = (_Float16*)(ws + OFF_QU);
    _Float16* q_news  = (_Float16*)(ws + OFF_QN);
    _Float16* agg_u   = (_Float16*)(ws + OFF_AGU);
    _Float16* agg_n   = (_Float16*)(ws + OFF_AGN);
    _Float16* kv_big  = (_Float16*)(ws + OFF_KVB);
    _Float16* kv_sm   = (_Float16*)(ws + OFF_KVS);
    _Float16* wkf = (_Float16*)(ws + OFF_WF);
    _Float16* wvf = wkf + 3 * 16384;
    _Float16* wqf = wvf + 3 * 16384;
    _Float16* waf = wqf + 2 * 16384;
    float* bke = ws + OFF_BE;
    float* bve = bke + 3 * 128;
    int* ib   = (int*)(ws + OFF_INT);
    int* cu   = ib + IO_CU;
    int* jrp  = ib + IO_JRP;
    int* bsum = ib + IO_BSUM;
    int* boff = ib + IO_BOFF;
    int* cl   = ib + IO_CL;
    const int* rp0 = jrp;
    const int* rp1 = jrp + NNEWS;
    const int* rp2 = jrp + NNEWS + NUSER;

    // ---- CSR build ----
    zero_i_kernel<<<(NTOT + 255) / 256, 256, 0, stream>>>(cu, NTOT);
    int g3e = (3 * NE + 255) / 256;
    hist3_kernel<<<g3e, 256, 0, stream>>>(ei0, ei1, ei2, cu);
    scan_part_kernel<<<NSB, 256, 0, stream>>>(cu, bsum);
    scan_top_kernel<<<1, 1024, 0, stream>>>(bsum, boff, jrp);
    scan_fin_kernel<<<NSB, 256, 0, stream>>>(cu, boff, jrp, cu);   // cu becomes cursors
    fill3_kernel<<<g3e, 256, 0, stream>>>(ei0, ei1, ei2, cu, cl);

    float* out_user = (float*)d_out;
    float* out_news = (float*)d_out + (size_t)NUSER * CH;

    for (int l = 0; l < 2; ++l) {
        const float* xu = l ? (const float*)out_user : x_user;
        const float* xn = l ? (const float*)out_news : x_news;

        eff_weights_kernel<<<6, 256, 0, stream>>>(
            Wk + (size_t)l * 2 * 16384, bk + (size_t)l * 2 * 128,
            Wv + (size_t)l * 2 * 16384, bv + (size_t)l * 2 * 128,
            a_rel + (size_t)l * 3 * 4096, m_rel + (size_t)l * 3 * 4096,
            p_rel + (size_t)l * 12, wkf, bke, wvf, bve);
        wt_convert_kernel<<<4, 256, 0, stream>>>(Wq + (size_t)l * 2 * 16384,
                                                 Wa + (size_t)l * 2 * 16384, wqf, waf);

        int gbU = (NUSER + 63) / 64, gbN = (NNEWS + 63) / 64;

        // q projections (fp16, stride 128)
        gemm_v2<1, false, false, false, true><<<gbU, 256, 0, stream>>>(
            xu, wqf, nullptr, bq + (size_t)(l * 2 + 0) * 128, nullptr,
            q_user, nullptr, 128, NUSER, nullptr, nullptr);
        gemm_v2<1, false, false, false, true><<<gbN, 256, 0, stream>>>(
            xn, wqf + 16384, nullptr, bq + (size_t)(l * 2 + 1) * 128, nullptr,
            q_news, nullptr, 128, NNEWS, nullptr, nullptr);

        // rel0 K/V (user src) -> kv_big, then news attention
        gemm_v2<2, false, false, false, true><<<gbU, 256, 0, stream>>>(
            xu, wkf, wvf, bke, bve,
            kv_big, kv_big + 128, 256, NUSER, nullptr, nullptr);
        attn_v2<<<(NNEWS + 3) / 4, 256, 0, stream>>>(
            q_news, kv_big, rp0, nullptr, nullptr, cl, agg_n, NNEWS, 0);

        // rel1 K/V (news src) -> kv_sm ; rel2 K/V (user src) -> kv_big (reuse, stream-ordered)
        gemm_v2<2, false, false, false, true><<<gbN, 256, 0, stream>>>(
            xn, wkf + 16384, wvf + 16384, bke + 128, bve + 128,
            kv_sm, kv_sm + 128, 256, NNEWS, nullptr, nullptr);
        gemm_v2<2, false, false, false, true><<<gbU, 256, 0, stream>>>(
            xu, wkf + 32768, wvf + 32768, bke + 256, bve + 256,
            kv_big, kv_big + 128, 256, NUSER, nullptr, nullptr);
        attn_v2<<<(NUSER + 3) / 4, 256, 0, stream>>>(
            q_user, kv_sm, rp1, kv_big, rp2, cl, agg_u, NUSER, 1);

        // output transform: relu(sig(skip)*(gelu(agg)@Wa + ba) + (1-sig)*x) [in-place safe]
        gemm_v2<1, true, true, true, false><<<gbU, 256, 0, stream>>>(
            agg_u, waf, nullptr, ba + (size_t)(l * 2 + 0) * 128, nullptr,
            out_user, nullptr, 128, NUSER, skip + l * 2 + 0, xu);
        gemm_v2<1, true, true, true, false><<<gbN, 256, 0, stream>>>(
            agg_n, waf + 16384, nullptr, ba + (size_t)(l * 2 + 1) * 128, nullptr,
            out_news, nullptr, 128, NNEWS, skip + l * 2 + 1, xn);
    }
    (void)in_sizes; (void)n_in; (void)out_size; (void)ws_size;
}

// Round 5
// 875.500 us; speedup vs baseline: 2.1246x; 1.1388x over previous
//
#include <hip/hip_runtime.h>
#include <cmath>

// ---------------- problem constants ----------------
constexpr int NUSER = 100000;
constexpr int NNEWS = 20000;
constexpr int CH    = 128;
constexpr int NE    = 250000;
constexpr int NTOT  = NNEWS + NUSER + NUSER;   // joint counter array (rel0|rel1|rel2)
constexpr int NSB   = (NTOT + 255) / 256;      // scan blocks = 860

typedef _Float16 f16x8 __attribute__((ext_vector_type(8)));
typedef _Float16 f16x4 __attribute__((ext_vector_type(4)));
typedef float    f32x4 __attribute__((ext_vector_type(4)));

// ---------------- workspace layout (float units) ----------------
constexpr size_t OFF_QU  = 0;                                   // q_user fp16 [NUSER*128]
constexpr size_t OFF_QN  = OFF_QU  + (size_t)NUSER * 64;        // q_news fp16
constexpr size_t OFF_AGU = OFF_QN  + (size_t)NNEWS * 64;        // agg_user fp16
constexpr size_t OFF_AGN = OFF_AGU + (size_t)NUSER * 64;        // agg_news fp16
constexpr size_t OFF_KVB = OFF_AGN + (size_t)NNEWS * 64;        // kv_big fp16 [NUSER][256] (k|v interleaved)
constexpr size_t OFF_KVS = OFF_KVB + (size_t)NUSER * 128;       // kv_sm  fp16 [NNEWS][256]
constexpr size_t OFF_WF  = OFF_KVS + (size_t)NNEWS * 128;       // swizzled fp16 frags: wk[3],wv[3],wq[2],wa[2]
constexpr size_t OFF_BE  = OFF_WF  + 10 * 8192;                 // bke[3*128]+bve[3*128] f32
constexpr size_t OFF_INT = OFF_BE  + 6 * 128;
// int offsets (relative, units: int)
constexpr size_t IO_CU   = 0;                    // joint counters/cursors [NTOT]
constexpr size_t IO_JRP  = IO_CU  + NTOT;        // joint row_ptr [NTOT+1]
constexpr size_t IO_BSUM = IO_JRP + NTOT + 1;    // scan partials [NSB]
constexpr size_t IO_BOFF = IO_BSUM + NSB;        // scan offsets  [NSB]
constexpr size_t IO_CL   = IO_BOFF + NSB;        // col (global slots) [3*NE]

__device__ __forceinline__ float gelu_f(float x) {
    return 0.5f * x * (1.0f + erff(x * 0.70710678118654752440f));
}

__global__ void zero_i_kernel(int* __restrict__ p, int n) {
    int i = blockIdx.x * 256 + threadIdx.x;
    if (i < n) p[i] = 0;
}

// ---------------- CSR build (joint counter array) ----------------
__global__ void hist3_kernel(const int* __restrict__ e0, const int* __restrict__ e1,
                             const int* __restrict__ e2, int* __restrict__ cu) {
    int idx = blockIdx.x * 256 + threadIdx.x;
    if (idx >= 3 * NE) return;
    int r = idx / NE, e = idx - r * NE;
    const int* ei = (r == 0) ? e0 : (r == 1) ? e1 : e2;
    int base = (r == 0) ? 0 : (r == 1) ? NNEWS : (NNEWS + NUSER);
    atomicAdd(&cu[base + ei[NE + e]], 1);
}

__global__ __launch_bounds__(256) void scan_part_kernel(const int* __restrict__ cu,
                                                        int* __restrict__ bsum) {
    int i = blockIdx.x * 256 + threadIdx.x;
    int v = (i < NTOT) ? cu[i] : 0;
    #pragma unroll
    for (int o = 1; o < 64; o <<= 1) v += __shfl_xor(v, o);
    __shared__ int ws_[4];
    if ((threadIdx.x & 63) == 0) ws_[threadIdx.x >> 6] = v;
    __syncthreads();
    if (threadIdx.x == 0) bsum[blockIdx.x] = ws_[0] + ws_[1] + ws_[2] + ws_[3];
}

__global__ __launch_bounds__(1024) void scan_top_kernel(const int* __restrict__ bsum,
                                                        int* __restrict__ boff,
                                                        int* __restrict__ jrp) {
    __shared__ int wsum[16];
    int tid = threadIdx.x, lane = tid & 63, w = tid >> 6;
    int v = (tid < NSB) ? bsum[tid] : 0;
    int x = v;
    #pragma unroll
    for (int o = 1; o < 64; o <<= 1) { int y = __shfl_up(x, o); if (lane >= o) x += y; }
    if (lane == 63) wsum[w] = x;
    __syncthreads();
    if (tid < 16) {
        int t = wsum[tid];
        #pragma unroll
        for (int o = 1; o < 16; o <<= 1) { int y = __shfl_up(t, o); if (tid >= o) t += y; }
        wsum[tid] = t;
    }
    __syncthreads();
    int woff = w ? wsum[w - 1] : 0;
    if (tid < NSB) boff[tid] = woff + x - v;
    if (tid == 0) jrp[NTOT] = 3 * NE;
}

__global__ __launch_bounds__(256) void scan_fin_kernel(const int* __restrict__ cu,
                                                       const int* __restrict__ boff,
                                                       int* __restrict__ jrp,
                                                       int* __restrict__ cur) {
    __shared__ int wsum[4];
    int tid = threadIdx.x, lane = tid & 63, w = tid >> 6;
    int i = blockIdx.x * 256 + tid;
    int v = (i < NTOT) ? cu[i] : 0;
    int x = v;
    #pragma unroll
    for (int o = 1; o < 64; o <<= 1) { int y = __shfl_up(x, o); if (lane >= o) x += y; }
    if (lane == 63) wsum[w] = x;
    __syncthreads();
    int woff = 0;
    #pragma unroll
    for (int k = 0; k < 4; ++k) if (k < w) woff += wsum[k];
    int excl = boff[blockIdx.x] + woff + x - v;
    if (i < NTOT) { jrp[i] = excl; cur[i] = excl; }
}

__global__ void fill3_kernel(const int* __restrict__ e0, const int* __restrict__ e1,
                             const int* __restrict__ e2,
                             int* __restrict__ cur, int* __restrict__ cl) {
    int idx = blockIdx.x * 256 + threadIdx.x;
    if (idx >= 3 * NE) return;
    int r = idx / NE, e = idx - r * NE;
    const int* ei = (r == 0) ? e0 : (r == 1) ? e1 : e2;
    int base = (r == 0) ? 0 : (r == 1) ? NNEWS : (NNEWS + NUSER);
    int dst = ei[NE + e], src = ei[e];
    int p = atomicAdd(&cur[base + dst], 1);
    cl[p] = src;
}

// ---------------- swizzled-fragment dest index ----------------
// MFMA 16x16x32 fragment (lane,j): idx = lane&15, k = (lane>>4)*8 + j.
// Wf layout: [kt][ct][lane][j] contiguous -> coalesced b128 stage, conflict-free ds_read_b128.
__device__ __forceinline__ int frag_dest(int k, int col) {
    int kt = k >> 5, quad = (k >> 3) & 3, j = k & 7;
    int ct = col >> 4, m = col & 15;
    int lane = quad * 16 + m;
    return ((kt * 8 + ct) * 64 + lane) * 8 + j;
}

// ---------------- effective weights (fold a_rel/m_rel/p_rel), swizzled fp16 ----------------
__global__ void eff_weights_kernel(const float* __restrict__ Wk, const float* __restrict__ bk,
                                   const float* __restrict__ Wv, const float* __restrict__ bv,
                                   const float* __restrict__ a_rel, const float* __restrict__ m_rel,
                                   const float* __restrict__ p_rel,
                                   _Float16* __restrict__ wkf, float* __restrict__ bke,
                                   _Float16* __restrict__ wvf, float* __restrict__ bve) {
    int b = blockIdx.x;         // 0..5
    int kind = b / 3;           // 0 = K, 1 = V
    int r = b % 3;
    const int st = (r == 1) ? 1 : 0;
    const float* W   = (kind ? Wv : Wk) + (size_t)st * 16384;
    const float* bi  = (kind ? bv : bk) + (size_t)st * 128;
    const float* rel = (kind ? m_rel : a_rel) + (size_t)r * 4096;
    _Float16* Wf = (kind ? wvf : wkf) + (size_t)r * 16384;
    float*    be = (kind ? bve : bke) + (size_t)r * 128;
    const float invsq = 0.17677669529663688f;   // 1/sqrt(32)
    for (int o = threadIdx.x; o < 16384; o += 256) {
        int k = o >> 7, col = o & 127, h = col >> 5, e = col & 31;
        const float* wrow = W + (size_t)k * 128 + h * 32;
        const float* rcol = rel + h * 1024 + e;
        float s = 0.f;
        #pragma unroll
        for (int d = 0; d < 32; ++d) s += wrow[d] * rcol[d * 32];
        if (kind == 0) s *= p_rel[r * 4 + h] * invsq;
        Wf[frag_dest(k, col)] = (_Float16)s;
    }
    if (threadIdx.x < 128) {
        int col = threadIdx.x, h = col >> 5, e = col & 31;
        float s = 0.f;
        #pragma unroll
        for (int d = 0; d < 32; ++d) s += bi[h * 32 + d] * rel[h * 1024 + d * 32 + e];
        if (kind == 0) s *= p_rel[r * 4 + h] * invsq;
        be[col] = s;
    }
}

__global__ void wt_convert_kernel(const float* __restrict__ Wq, const float* __restrict__ Wa,
                                  _Float16* __restrict__ wqf, _Float16* __restrict__ waf) {
    int b = blockIdx.x;  // 0,1: Wq types; 2,3: Wa types
    const float* W  = (b < 2) ? (Wq + (size_t)b * 16384) : (Wa + (size_t)(b - 2) * 16384);
    _Float16*   Wf = (b < 2) ? (wqf + (size_t)b * 16384) : (waf + (size_t)(b - 2) * 16384);
    for (int o = threadIdx.x; o < 16384; o += 256) {
        int k = o >> 7, col = o & 127;
        Wf[frag_dest(k, col)] = (_Float16)W[o];
    }
}

// ---------------- MFMA GEMM, weights staged in LDS (fixes R4 latency serialization) ----------------
// Block = 4 waves = 64 nodes. Per wave: 16 nodes x 128 out-ch.
// mfma(A=Wfrag, B=Xfrag): D col = node (lane&15), D rows = out-ch (quad*4+reg) -> x4 stores.
// Wf already in fragment-lane order: LDS stage is a straight copy; ds_read_b128 conflict-free.
template<int NOUT, bool IN_HALF, bool GELU_IN, bool SKIP_OUT, bool OUT_HALF>
__global__ __launch_bounds__(256) void gemm_v3(
    const void* __restrict__ Ain,
    const _Float16* __restrict__ Wf0, const _Float16* __restrict__ Wf1,
    const float* __restrict__ b0, const float* __restrict__ b1,
    void* __restrict__ out0, void* __restrict__ out1, int ostride,
    int N, const float* __restrict__ skipv, const float* __restrict__ Xold)
{
    __shared__ _Float16 sW[NOUT * 16384];   // 32 KB per weight matrix
    const int tid = threadIdx.x;

    // cooperative stage: coalesced 16B chunks (8 iters per thread per matrix)
    for (int i = tid; i < NOUT * 2048; i += 256) {
        const _Float16* src = (NOUT == 1 || i < 2048) ? (Wf0 + (size_t)i * 8)
                                                      : (Wf1 + (size_t)(i - 2048) * 8);
        *(f16x8*)(sW + (size_t)i * 8) = *(const f16x8*)src;
    }
    __syncthreads();

    const int wv   = blockIdx.x * 4 + (tid >> 6);
    const int lane = tid & 63;
    const int m = lane & 15, quad = lane >> 4;
    const int node  = wv * 16 + m;
    const int nodec = (node < N) ? node : (N - 1);   // clamped for loads (wave stays in barrier)

    f32x4 acc0[8], acc1[8];
    #pragma unroll
    for (int t = 0; t < 8; ++t) {
        acc0[t] = (f32x4){0.f, 0.f, 0.f, 0.f};
        if (NOUT > 1) acc1[t] = (f32x4){0.f, 0.f, 0.f, 0.f};
    }

    #pragma unroll
    for (int kt = 0; kt < 4; ++kt) {
        f16x8 xf;
        if (IN_HALF) {
            xf = *(const f16x8*)((const _Float16*)Ain + (size_t)nodec * 128 + kt * 32 + quad * 8);
            if (GELU_IN) {
                #pragma unroll
                for (int j = 0; j < 8; ++j) xf[j] = (_Float16)gelu_f((float)xf[j]);
            }
        } else {
            const float* Af = (const float*)Ain + (size_t)nodec * 128 + kt * 32 + quad * 8;
            f32x4 a0 = *(const f32x4*)Af;
            f32x4 a1 = *(const f32x4*)(Af + 4);
            if (GELU_IN) {
                #pragma unroll
                for (int j = 0; j < 4; ++j) { a0[j] = gelu_f(a0[j]); a1[j] = gelu_f(a1[j]); }
            }
            xf = (f16x8){(_Float16)a0[0], (_Float16)a0[1], (_Float16)a0[2], (_Float16)a0[3],
                         (_Float16)a1[0], (_Float16)a1[1], (_Float16)a1[2], (_Float16)a1[3]};
        }
        #pragma unroll
        for (int ct = 0; ct < 8; ++ct) {
            f16x8 wf0 = *(const f16x8*)(sW + ((kt * 8 + ct) * 64 + lane) * 8);
            acc0[ct] = __builtin_amdgcn_mfma_f32_16x16x32_f16(wf0, xf, acc0[ct], 0, 0, 0);
            if (NOUT > 1) {
                f16x8 wf1 = *(const f16x8*)(sW + 16384 + ((kt * 8 + ct) * 64 + lane) * 8);
                acc1[ct] = __builtin_amdgcn_mfma_f32_16x16x32_f16(wf1, xf, acc1[ct], 0, 0, 0);
            }
        }
    }

    if (node >= N) return;   // after all barriers: safe

    float aS = 0.f, bSk = 0.f;
    if (SKIP_OUT) {
        float sv = skipv[0];
        aS = 1.0f / (1.0f + expf(-sv));
        bSk = 1.0f - aS;
    }
    #pragma unroll
    for (int ct = 0; ct < 8; ++ct) {
        int c = ct * 16 + quad * 4;      // out-channel base for this lane's 4 regs
        {
            f32x4 r = acc0[ct] + *(const f32x4*)(b0 + c);
            if (SKIP_OUT) {
                f32x4 xo = *(const f32x4*)(Xold + (size_t)node * 128 + c);
                #pragma unroll
                for (int j = 0; j < 4; ++j) r[j] = fmaxf(aS * r[j] + bSk * xo[j], 0.f);
            }
            if (OUT_HALF) {
                f16x4 h = {(_Float16)r[0], (_Float16)r[1], (_Float16)r[2], (_Float16)r[3]};
                *(f16x4*)((_Float16*)out0 + (size_t)node * ostride + c) = h;
            } else {
                *(f32x4*)((float*)out0 + (size_t)node * ostride + c) = r;
            }
        }
        if (NOUT > 1) {
            f32x4 r = acc1[ct] + *(const f32x4*)(b1 + c);
            f16x4 h = {(_Float16)r[0], (_Float16)r[1], (_Float16)r[2], (_Float16)r[3]};
            *(f16x4*)((_Float16*)out1 + (size_t)node * ostride + c) = h;
        }
    }
}

// ---------------- attention: 1 node/wave, 2 edges/iter (32 lanes x f16x4 each) ----------------
// kv interleaved [node][k0..k127 | v0..v127] fp16 -> one 512B row per edge.
__global__ __launch_bounds__(256) void attn_v2(
    const _Float16* __restrict__ q,
    const _Float16* __restrict__ kv1, const int* __restrict__ rp1,
    const _Float16* __restrict__ kv2, const int* __restrict__ rp2,
    const int* __restrict__ cl,
    _Float16* __restrict__ agg, int Ndst, int two)
{
    int d = blockIdx.x * 4 + (threadIdx.x >> 6);
    if (d >= Ndst) return;
    const int lane = threadIdx.x & 63;
    const int half = lane >> 5;          // which edge of the pair
    const int c4 = lane & 31;            // channels c4*4 .. +3 ; head = c4>>3
    f16x4 qh = *(const f16x4*)(q + (size_t)d * 128 + c4 * 4);
    float q0 = (float)qh[0], q1 = (float)qh[1], q2 = (float)qh[2], q3 = (float)qh[3];
    float a0 = 0.f, a1 = 0.f, a2 = 0.f, a3 = 0.f;
    for (int rel = 0; rel < 1 + two; ++rel) {
        const _Float16* kv = rel ? kv2 : kv1;
        const int* rp = rel ? rp2 : rp1;
        int e0 = rp[d], e1 = rp[d + 1];
        float den = 0.f, s0 = 0.f, s1 = 0.f, s2 = 0.f, s3 = 0.f;
        for (int e = e0; e < e1; e += 2) {
            int el = e + half;
            bool valid = el < e1;
            int s = cl[valid ? el : e];
            const _Float16* row = kv + (size_t)s * 256;
            f16x4 kk = *(const f16x4*)(row + c4 * 4);
            f16x4 vv = *(const f16x4*)(row + 128 + c4 * 4);
            float p = q0 * (float)kk[0] + q1 * (float)kk[1]
                    + q2 * (float)kk[2] + q3 * (float)kk[3];
            p += __shfl_xor(p, 1);
            p += __shfl_xor(p, 2);
            p += __shfl_xor(p, 4);       // 8 lanes per head
            float w = valid ? expf(p) : 0.f;
            den += w;
            s0 += w * (float)vv[0]; s1 += w * (float)vv[1];
            s2 += w * (float)vv[2]; s3 += w * (float)vv[3];
        }
        den += __shfl_xor(den, 32);      // combine edge-halves
        s0 += __shfl_xor(s0, 32); s1 += __shfl_xor(s1, 32);
        s2 += __shfl_xor(s2, 32); s3 += __shfl_xor(s3, 32);
        if (den > 0.f) {
            float inv = 1.f / den;
            a0 += s0 * inv; a1 += s1 * inv; a2 += s2 * inv; a3 += s3 * inv;
        }
    }
    if (half == 0) {
        f16x4 o = {(_Float16)a0, (_Float16)a1, (_Float16)a2, (_Float16)a3};
        *(f16x4*)(agg + (size_t)d * 128 + c4 * 4) = o;
    }
}

// ---------------- orchestration ----------------
extern "C" void kernel_launch(void* const* d_in, const int* in_sizes, int n_in,
                              void* d_out, int out_size, void* d_ws, size_t ws_size,
                              hipStream_t stream)
{
    const float* x_user = (const float*)d_in[0];
    const float* x_news = (const float*)d_in[1];
    const int* ei0 = (const int*)d_in[2];
    const int* ei1 = (const int*)d_in[3];
    const int* ei2 = (const int*)d_in[4];
    const float* Wk = (const float*)d_in[5];
    const float* bk = (const float*)d_in[6];
    const float* Wq = (const float*)d_in[7];
    const float* bq = (const float*)d_in[8];
    const float* Wv = (const float*)d_in[9];
    const float* bv = (const float*)d_in[10];
    const float* Wa = (const float*)d_in[11];
    const float* ba = (const float*)d_in[12];
    const float* skip = (const float*)d_in[13];
    const float* a_rel = (const float*)d_in[14];
    const float* m_rel = (const float*)d_in[15];
    const float* p_rel = (const float*)d_in[16];

    float* ws = (float*)d_ws;
    _Float16* q_user  = (_Float16*)(ws + OFF_QU);
    _Float16* q_news  = (_Float16*)(ws + OFF_QN);
    _Float16* agg_u   = (_Float16*)(ws + OFF_AGU);
    _Float16* agg_n   = (_Float16*)(ws + OFF_AGN);
    _Float16* kv_big  = (_Float16*)(ws + OFF_KVB);
    _Float16* kv_sm   = (_Float16*)(ws + OFF_KVS);
    _Float16* wkf = (_Float16*)(ws + OFF_WF);
    _Float16* wvf = wkf + 3 * 16384;
    _Float16* wqf = wvf + 3 * 16384;
    _Float16* waf = wqf + 2 * 16384;
    float* bke = ws + OFF_BE;
    float* bve = bke + 3 * 128;
    int* ib   = (int*)(ws + OFF_INT);
    int* cu   = ib + IO_CU;
    int* jrp  = ib + IO_JRP;
    int* bsum = ib + IO_BSUM;
    int* boff = ib + IO_BOFF;
    int* cl   = ib + IO_CL;
    const int* rp0 = jrp;
    const int* rp1 = jrp + NNEWS;
    const int* rp2 = jrp + NNEWS + NUSER;

    // ---- CSR build ----
    zero_i_kernel<<<(NTOT + 255) / 256, 256, 0, stream>>>(cu, NTOT);
    int g3e = (3 * NE + 255) / 256;
    hist3_kernel<<<g3e, 256, 0, stream>>>(ei0, ei1, ei2, cu);
    scan_part_kernel<<<NSB, 256, 0, stream>>>(cu, bsum);
    scan_top_kernel<<<1, 1024, 0, stream>>>(bsum, boff, jrp);
    scan_fin_kernel<<<NSB, 256, 0, stream>>>(cu, boff, jrp, cu);   // cu becomes cursors
    fill3_kernel<<<g3e, 256, 0, stream>>>(ei0, ei1, ei2, cu, cl);

    float* out_user = (float*)d_out;
    float* out_news = (float*)d_out + (size_t)NUSER * CH;

    for (int l = 0; l < 2; ++l) {
        const float* xu = l ? (const float*)out_user : x_user;
        const float* xn = l ? (const float*)out_news : x_news;

        eff_weights_kernel<<<6, 256, 0, stream>>>(
            Wk + (size_t)l * 2 * 16384, bk + (size_t)l * 2 * 128,
            Wv + (size_t)l * 2 * 16384, bv + (size_t)l * 2 * 128,
            a_rel + (size_t)l * 3 * 4096, m_rel + (size_t)l * 3 * 4096,
            p_rel + (size_t)l * 12, wkf, bke, wvf, bve);
        wt_convert_kernel<<<4, 256, 0, stream>>>(Wq + (size_t)l * 2 * 16384,
                                                 Wa + (size_t)l * 2 * 16384, wqf, waf);

        int gbU = (NUSER + 63) / 64, gbN = (NNEWS + 63) / 64;

        // q projections (fp16, stride 128)
        gemm_v3<1, false, false, false, true><<<gbU, 256, 0, stream>>>(
            xu, wqf, nullptr, bq + (size_t)(l * 2 + 0) * 128, nullptr,
            q_user, nullptr, 128, NUSER, nullptr, nullptr);
        gemm_v3<1, false, false, false, true><<<gbN, 256, 0, stream>>>(
            xn, wqf + 16384, nullptr, bq + (size_t)(l * 2 + 1) * 128, nullptr,
            q_news, nullptr, 128, NNEWS, nullptr, nullptr);

        // rel0 K/V (user src) -> kv_big, then news attention
        gemm_v3<2, false, false, false, true><<<gbU, 256, 0, stream>>>(
            xu, wkf, wvf, bke, bve,
            kv_big, kv_big + 128, 256, NUSER, nullptr, nullptr);
        attn_v2<<<(NNEWS + 3) / 4, 256, 0, stream>>>(
            q_news, kv_big, rp0, nullptr, nullptr, cl, agg_n, NNEWS, 0);

        // rel1 K/V (news src) -> kv_sm ; rel2 K/V (user src) -> kv_big (reuse, stream-ordered)
        gemm_v3<2, false, false, false, true><<<gbN, 256, 0, stream>>>(
            xn, wkf + 16384, wvf + 16384, bke + 128, bve + 128,
            kv_sm, kv_sm + 128, 256, NNEWS, nullptr, nullptr);
        gemm_v3<2, false, false, false, true><<<gbU, 256, 0, stream>>>(
            xu, wkf + 32768, wvf + 32768, bke + 256, bve + 256,
            kv_big, kv_big + 128, 256, NUSER, nullptr, nullptr);
        attn_v2<<<(NUSER + 3) / 4, 256, 0, stream>>>(
            q_user, kv_sm, rp1, kv_big, rp2, cl, agg_u, NUSER, 1);

        // output transform: relu(sig(skip)*(gelu(agg)@Wa + ba) + (1-sig)*x) [in-place safe]
        gemm_v3<1, true, true, true, false><<<gbU, 256, 0, stream>>>(
            agg_u, waf, nullptr, ba + (size_t)(l * 2 + 0) * 128, nullptr,
            out_user, nullptr, 128, NUSER, skip + l * 2 + 0, xu);
        gemm_v3<1, true, true, true, false><<<gbN, 256, 0, stream>>>(
            agg_n, waf + 16384, nullptr, ba + (size_t)(l * 2 + 1) * 128, nullptr,
            out_news, nullptr, 128, NNEWS, skip + l * 2 + 1, xn);
    }
    (void)in_sizes; (void)n_in; (void)out_size; (void)ws_size;
}

// Round 6
// 840.823 us; speedup vs baseline: 2.2123x; 1.0412x over previous
//
#include <hip/hip_runtime.h>
#include <cmath>

// ---------------- problem constants ----------------
constexpr int NUSER = 100000;
constexpr int NNEWS = 20000;
constexpr int CH    = 128;
constexpr int NE    = 250000;
constexpr int NTOT  = NNEWS + NUSER + NUSER;   // joint counter array (rel0|rel1|rel2)
constexpr int NSB   = (NTOT + 255) / 256;      // scan blocks = 860

typedef _Float16 f16x8 __attribute__((ext_vector_type(8)));
typedef _Float16 f16x4 __attribute__((ext_vector_type(4)));
typedef _Float16 f16x2 __attribute__((ext_vector_type(2)));
typedef float    f32x4 __attribute__((ext_vector_type(4)));

// ---------------- workspace layout (float units) ----------------
constexpr size_t OFF_QU  = 0;                                   // q_user fp16 [NUSER*128]
constexpr size_t OFF_QN  = OFF_QU  + (size_t)NUSER * 64;        // q_news fp16
constexpr size_t OFF_AGU = OFF_QN  + (size_t)NNEWS * 64;        // agg_user fp16
constexpr size_t OFF_AGN = OFF_AGU + (size_t)NUSER * 64;        // agg_news fp16
constexpr size_t OFF_KVB = OFF_AGN + (size_t)NNEWS * 64;        // kv_big fp16 [NUSER][256] (k|v interleaved)
constexpr size_t OFF_KVS = OFF_KVB + (size_t)NUSER * 128;       // kv_sm  fp16 [NNEWS][256]
constexpr size_t OFF_WF  = OFF_KVS + (size_t)NNEWS * 128;       // swizzled fp16 frags: wk[3],wv[3],wq[2],wa[2]
constexpr size_t OFF_BE  = OFF_WF  + 10 * 8192;                 // bke[3*128]+bve[3*128] f32
constexpr size_t OFF_INT = OFF_BE  + 6 * 128;
// int offsets (relative, units: int)
constexpr size_t IO_CU   = 0;                    // joint counters/cursors [NTOT]
constexpr size_t IO_JRP  = IO_CU  + NTOT;        // joint row_ptr [NTOT+1]
constexpr size_t IO_BSUM = IO_JRP + NTOT + 1;    // scan partials [NSB]
constexpr size_t IO_BOFF = IO_BSUM + NSB;        // scan offsets  [NSB]
constexpr size_t IO_CL   = IO_BOFF + NSB;        // col (global slots) [3*NE]

__device__ __forceinline__ float gelu_f(float x) {
    return 0.5f * x * (1.0f + erff(x * 0.70710678118654752440f));
}

__global__ void zero_i_kernel(int* __restrict__ p, int n) {
    int i = blockIdx.x * 256 + threadIdx.x;
    if (i < n) p[i] = 0;
}

// ---------------- CSR build (joint counter array) ----------------
__global__ void hist3_kernel(const int* __restrict__ e0, const int* __restrict__ e1,
                             const int* __restrict__ e2, int* __restrict__ cu) {
    int idx = blockIdx.x * 256 + threadIdx.x;
    if (idx >= 3 * NE) return;
    int r = idx / NE, e = idx - r * NE;
    const int* ei = (r == 0) ? e0 : (r == 1) ? e1 : e2;
    int base = (r == 0) ? 0 : (r == 1) ? NNEWS : (NNEWS + NUSER);
    atomicAdd(&cu[base + ei[NE + e]], 1);
}

__global__ __launch_bounds__(256) void scan_part_kernel(const int* __restrict__ cu,
                                                        int* __restrict__ bsum) {
    int i = blockIdx.x * 256 + threadIdx.x;
    int v = (i < NTOT) ? cu[i] : 0;
    #pragma unroll
    for (int o = 1; o < 64; o <<= 1) v += __shfl_xor(v, o);
    __shared__ int ws_[4];
    if ((threadIdx.x & 63) == 0) ws_[threadIdx.x >> 6] = v;
    __syncthreads();
    if (threadIdx.x == 0) bsum[blockIdx.x] = ws_[0] + ws_[1] + ws_[2] + ws_[3];
}

__global__ __launch_bounds__(1024) void scan_top_kernel(const int* __restrict__ bsum,
                                                        int* __restrict__ boff,
                                                        int* __restrict__ jrp) {
    __shared__ int wsum[16];
    int tid = threadIdx.x, lane = tid & 63, w = tid >> 6;
    int v = (tid < NSB) ? bsum[tid] : 0;
    int x = v;
    #pragma unroll
    for (int o = 1; o < 64; o <<= 1) { int y = __shfl_up(x, o); if (lane >= o) x += y; }
    if (lane == 63) wsum[w] = x;
    __syncthreads();
    if (tid < 16) {
        int t = wsum[tid];
        #pragma unroll
        for (int o = 1; o < 16; o <<= 1) { int y = __shfl_up(t, o); if (tid >= o) t += y; }
        wsum[tid] = t;
    }
    __syncthreads();
    int woff = w ? wsum[w - 1] : 0;
    if (tid < NSB) boff[tid] = woff + x - v;
    if (tid == 0) jrp[NTOT] = 3 * NE;
}

__global__ __launch_bounds__(256) void scan_fin_kernel(const int* __restrict__ cu,
                                                       const int* __restrict__ boff,
                                                       int* __restrict__ jrp,
                                                       int* __restrict__ cur) {
    __shared__ int wsum[4];
    int tid = threadIdx.x, lane = tid & 63, w = tid >> 6;
    int i = blockIdx.x * 256 + tid;
    int v = (i < NTOT) ? cu[i] : 0;
    int x = v;
    #pragma unroll
    for (int o = 1; o < 64; o <<= 1) { int y = __shfl_up(x, o); if (lane >= o) x += y; }
    if (lane == 63) wsum[w] = x;
    __syncthreads();
    int woff = 0;
    #pragma unroll
    for (int k = 0; k < 4; ++k) if (k < w) woff += wsum[k];
    int excl = boff[blockIdx.x] + woff + x - v;
    if (i < NTOT) { jrp[i] = excl; cur[i] = excl; }
}

__global__ void fill3_kernel(const int* __restrict__ e0, const int* __restrict__ e1,
                             const int* __restrict__ e2,
                             int* __restrict__ cur, int* __restrict__ cl) {
    int idx = blockIdx.x * 256 + threadIdx.x;
    if (idx >= 3 * NE) return;
    int r = idx / NE, e = idx - r * NE;
    const int* ei = (r == 0) ? e0 : (r == 1) ? e1 : e2;
    int base = (r == 0) ? 0 : (r == 1) ? NNEWS : (NNEWS + NUSER);
    int dst = ei[NE + e], src = ei[e];
    int p = atomicAdd(&cur[base + dst], 1);
    cl[p] = src;
}

// ---------------- swizzled-fragment dest index ----------------
// MFMA 16x16x32 fragment (lane,j): idx = lane&15, k = (lane>>4)*8 + j.
// Wf layout: [kt][ct][lane][j] contiguous -> coalesced b128 stage, conflict-free ds_read_b128.
__device__ __forceinline__ int frag_dest(int k, int col) {
    int kt = k >> 5, quad = (k >> 3) & 3, j = k & 7;
    int ct = col >> 4, m = col & 15;
    int lane = quad * 16 + m;
    return ((kt * 8 + ct) * 64 + lane) * 8 + j;
}

// ---------------- effective weights (fold a_rel/m_rel/p_rel), swizzled fp16 ----------------
__global__ void eff_weights_kernel(const float* __restrict__ Wk, const float* __restrict__ bk,
                                   const float* __restrict__ Wv, const float* __restrict__ bv,
                                   const float* __restrict__ a_rel, const float* __restrict__ m_rel,
                                   const float* __restrict__ p_rel,
                                   _Float16* __restrict__ wkf, float* __restrict__ bke,
                                   _Float16* __restrict__ wvf, float* __restrict__ bve) {
    int b = blockIdx.x;         // 0..5
    int kind = b / 3;           // 0 = K, 1 = V
    int r = b % 3;
    const int st = (r == 1) ? 1 : 0;
    const float* W   = (kind ? Wv : Wk) + (size_t)st * 16384;
    const float* bi  = (kind ? bv : bk) + (size_t)st * 128;
    const float* rel = (kind ? m_rel : a_rel) + (size_t)r * 4096;
    _Float16* Wf = (kind ? wvf : wkf) + (size_t)r * 16384;
    float*    be = (kind ? bve : bke) + (size_t)r * 128;
    const float invsq = 0.17677669529663688f;   // 1/sqrt(32)
    for (int o = threadIdx.x; o < 16384; o += 256) {
        int k = o >> 7, col = o & 127, h = col >> 5, e = col & 31;
        const float* wrow = W + (size_t)k * 128 + h * 32;
        const float* rcol = rel + h * 1024 + e;
        float s = 0.f;
        #pragma unroll
        for (int d = 0; d < 32; ++d) s += wrow[d] * rcol[d * 32];
        if (kind == 0) s *= p_rel[r * 4 + h] * invsq;
        Wf[frag_dest(k, col)] = (_Float16)s;
    }
    if (threadIdx.x < 128) {
        int col = threadIdx.x, h = col >> 5, e = col & 31;
        float s = 0.f;
        #pragma unroll
        for (int d = 0; d < 32; ++d) s += bi[h * 32 + d] * rel[h * 1024 + d * 32 + e];
        if (kind == 0) s *= p_rel[r * 4 + h] * invsq;
        be[col] = s;
    }
}

__global__ void wt_convert_kernel(const float* __restrict__ Wq, const float* __restrict__ Wa,
                                  _Float16* __restrict__ wqf, _Float16* __restrict__ waf) {
    int b = blockIdx.x;  // 0,1: Wq types; 2,3: Wa types
    const float* W  = (b < 2) ? (Wq + (size_t)b * 16384) : (Wa + (size_t)(b - 2) * 16384);
    _Float16*   Wf = (b < 2) ? (wqf + (size_t)b * 16384) : (waf + (size_t)(b - 2) * 16384);
    for (int o = threadIdx.x; o < 16384; o += 256) {
        int k = o >> 7, col = o & 127;
        Wf[frag_dest(k, col)] = (_Float16)W[o];
    }
}

// ---------------- MFMA GEMM, weights staged in LDS ----------------
// Block = 4 waves = 64 nodes. Per wave: 16 nodes x 128 out-ch.
// mfma(A=Wfrag, B=Xfrag): D col = node (lane&15), D rows = out-ch (quad*4+reg) -> x4 stores.
template<int NOUT, bool IN_HALF, bool GELU_IN, bool SKIP_OUT, bool OUT_HALF>
__global__ __launch_bounds__(256) void gemm_v3(
    const void* __restrict__ Ain,
    const _Float16* __restrict__ Wf0, const _Float16* __restrict__ Wf1,
    const float* __restrict__ b0, const float* __restrict__ b1,
    void* __restrict__ out0, void* __restrict__ out1, int ostride,
    int N, const float* __restrict__ skipv, const float* __restrict__ Xold)
{
    __shared__ _Float16 sW[NOUT * 16384];   // 32 KB per weight matrix
    const int tid = threadIdx.x;

    for (int i = tid; i < NOUT * 2048; i += 256) {
        const _Float16* src = (NOUT == 1 || i < 2048) ? (Wf0 + (size_t)i * 8)
                                                      : (Wf1 + (size_t)(i - 2048) * 8);
        *(f16x8*)(sW + (size_t)i * 8) = *(const f16x8*)src;
    }
    __syncthreads();

    const int wv   = blockIdx.x * 4 + (tid >> 6);
    const int lane = tid & 63;
    const int m = lane & 15, quad = lane >> 4;
    const int node  = wv * 16 + m;
    const int nodec = (node < N) ? node : (N - 1);   // clamped for loads

    f32x4 acc0[8], acc1[8];
    #pragma unroll
    for (int t = 0; t < 8; ++t) {
        acc0[t] = (f32x4){0.f, 0.f, 0.f, 0.f};
        if (NOUT > 1) acc1[t] = (f32x4){0.f, 0.f, 0.f, 0.f};
    }

    #pragma unroll
    for (int kt = 0; kt < 4; ++kt) {
        f16x8 xf;
        if (IN_HALF) {
            xf = *(const f16x8*)((const _Float16*)Ain + (size_t)nodec * 128 + kt * 32 + quad * 8);
            if (GELU_IN) {
                #pragma unroll
                for (int j = 0; j < 8; ++j) xf[j] = (_Float16)gelu_f((float)xf[j]);
            }
        } else {
            const float* Af = (const float*)Ain + (size_t)nodec * 128 + kt * 32 + quad * 8;
            f32x4 a0 = *(const f32x4*)Af;
            f32x4 a1 = *(const f32x4*)(Af + 4);
            if (GELU_IN) {
                #pragma unroll
                for (int j = 0; j < 4; ++j) { a0[j] = gelu_f(a0[j]); a1[j] = gelu_f(a1[j]); }
            }
            xf = (f16x8){(_Float16)a0[0], (_Float16)a0[1], (_Float16)a0[2], (_Float16)a0[3],
                         (_Float16)a1[0], (_Float16)a1[1], (_Float16)a1[2], (_Float16)a1[3]};
        }
        #pragma unroll
        for (int ct = 0; ct < 8; ++ct) {
            f16x8 wf0 = *(const f16x8*)(sW + ((kt * 8 + ct) * 64 + lane) * 8);
            acc0[ct] = __builtin_amdgcn_mfma_f32_16x16x32_f16(wf0, xf, acc0[ct], 0, 0, 0);
            if (NOUT > 1) {
                f16x8 wf1 = *(const f16x8*)(sW + 16384 + ((kt * 8 + ct) * 64 + lane) * 8);
                acc1[ct] = __builtin_amdgcn_mfma_f32_16x16x32_f16(wf1, xf, acc1[ct], 0, 0, 0);
            }
        }
    }

    if (node >= N) return;   // after all barriers: safe

    float aS = 0.f, bSk = 0.f;
    if (SKIP_OUT) {
        float sv = skipv[0];
        aS = 1.0f / (1.0f + expf(-sv));
        bSk = 1.0f - aS;
    }
    #pragma unroll
    for (int ct = 0; ct < 8; ++ct) {
        int c = ct * 16 + quad * 4;      // out-channel base for this lane's 4 regs
        {
            f32x4 r = acc0[ct] + *(const f32x4*)(b0 + c);
            if (SKIP_OUT) {
                f32x4 xo = *(const f32x4*)(Xold + (size_t)node * 128 + c);
                #pragma unroll
                for (int j = 0; j < 4; ++j) r[j] = fmaxf(aS * r[j] + bSk * xo[j], 0.f);
            }
            if (OUT_HALF) {
                f16x4 h = {(_Float16)r[0], (_Float16)r[1], (_Float16)r[2], (_Float16)r[3]};
                *(f16x4*)((_Float16*)out0 + (size_t)node * ostride + c) = h;
            } else {
                *(f32x4*)((float*)out0 + (size_t)node * ostride + c) = r;
            }
        }
        if (NOUT > 1) {
            f32x4 r = acc1[ct] + *(const f32x4*)(b1 + c);
            f16x4 h = {(_Float16)r[0], (_Float16)r[1], (_Float16)r[2], (_Float16)r[3]};
            *(f16x4*)((_Float16*)out1 + (size_t)node * ostride + c) = h;
        }
    }
}

// ---------------- attention v3: 1 node/wave, 4 edges/iter (16 lanes x f16x8 each) ----------------
// kv interleaved [node][k0..k127 | v0..v127] fp16 -> per edge: one 256B k read + 256B v read.
// Lane sub (0..15) covers channels sub*8..sub*8+7; head = sub>>2 (4 lanes per head).
__global__ __launch_bounds__(256) void attn_v3(
    const _Float16* __restrict__ q,
    const _Float16* __restrict__ kv1, const int* __restrict__ rp1,
    const _Float16* __restrict__ kv2, const int* __restrict__ rp2,
    const int* __restrict__ cl,
    _Float16* __restrict__ agg, int Ndst, int two)
{
    int d = blockIdx.x * 4 + (threadIdx.x >> 6);
    if (d >= Ndst) return;
    const int lane = threadIdx.x & 63;
    const int eg  = lane >> 4;           // edge group 0..3 (4 edges in flight)
    const int sub = lane & 15;           // 8 channels per lane
    f16x8 qh = *(const f16x8*)(q + (size_t)d * 128 + sub * 8);
    float acc[8] = {0.f, 0.f, 0.f, 0.f, 0.f, 0.f, 0.f, 0.f};

    for (int rel = 0; rel < 1 + two; ++rel) {
        const _Float16* kv = rel ? kv2 : kv1;
        const int* rp = rel ? rp2 : rp1;
        int e0 = rp[d], e1 = rp[d + 1];
        float den = 0.f;
        float s[8] = {0.f, 0.f, 0.f, 0.f, 0.f, 0.f, 0.f, 0.f};
        for (int e = e0; e < e1; e += 4) {
            int el = e + eg;
            bool valid = el < e1;
            int src = cl[valid ? el : e];
            const _Float16* row = kv + (size_t)src * 256;
            f16x8 kk = *(const f16x8*)(row + sub * 8);
            f16x8 vv = *(const f16x8*)(row + 128 + sub * 8);
            float p = 0.f;
#if __has_builtin(__builtin_amdgcn_fdot2)
            const f16x2* kp = (const f16x2*)&kk;
            const f16x2* qp = (const f16x2*)&qh;
            p = __builtin_amdgcn_fdot2(kp[0], qp[0], p, false);
            p = __builtin_amdgcn_fdot2(kp[1], qp[1], p, false);
            p = __builtin_amdgcn_fdot2(kp[2], qp[2], p, false);
            p = __builtin_amdgcn_fdot2(kp[3], qp[3], p, false);
#else
            #pragma unroll
            for (int j = 0; j < 8; ++j) p += (float)kk[j] * (float)qh[j];
#endif
            p += __shfl_xor(p, 1);
            p += __shfl_xor(p, 2);       // 4 lanes per head -> full 32-ch head dot
            float w = valid ? expf(p) : 0.f;   // p_rel/sqrt(D) folded into k
            den += w;
            #pragma unroll
            for (int j = 0; j < 8; ++j) s[j] += w * (float)vv[j];
        }
        // combine the 4 edge groups (same sub = same channels at lane^16, lane^32)
        den += __shfl_xor(den, 16);
        den += __shfl_xor(den, 32);
        #pragma unroll
        for (int j = 0; j < 8; ++j) {
            s[j] += __shfl_xor(s[j], 16);
            s[j] += __shfl_xor(s[j], 32);
        }
        if (den > 0.f) {
            float inv = 1.f / den;
            #pragma unroll
            for (int j = 0; j < 8; ++j) acc[j] += s[j] * inv;
        }
    }

    if (eg == 0) {
        f16x8 o;
        #pragma unroll
        for (int j = 0; j < 8; ++j) o[j] = (_Float16)acc[j];
        *(f16x8*)(agg + (size_t)d * 128 + sub * 8) = o;
    }
}

// ---------------- orchestration ----------------
extern "C" void kernel_launch(void* const* d_in, const int* in_sizes, int n_in,
                              void* d_out, int out_size, void* d_ws, size_t ws_size,
                              hipStream_t stream)
{
    const float* x_user = (const float*)d_in[0];
    const float* x_news = (const float*)d_in[1];
    const int* ei0 = (const int*)d_in[2];
    const int* ei1 = (const int*)d_in[3];
    const int* ei2 = (const int*)d_in[4];
    const float* Wk = (const float*)d_in[5];
    const float* bk = (const float*)d_in[6];
    const float* Wq = (const float*)d_in[7];
    const float* bq = (const float*)d_in[8];
    const float* Wv = (const float*)d_in[9];
    const float* bv = (const float*)d_in[10];
    const float* Wa = (const float*)d_in[11];
    const float* ba = (const float*)d_in[12];
    const float* skip = (const float*)d_in[13];
    const float* a_rel = (const float*)d_in[14];
    const float* m_rel = (const float*)d_in[15];
    const float* p_rel = (const float*)d_in[16];

    float* ws = (float*)d_ws;
    _Float16* q_user  = (_Float16*)(ws + OFF_QU);
    _Float16* q_news  = (_Float16*)(ws + OFF_QN);
    _Float16* agg_u   = (_Float16*)(ws + OFF_AGU);
    _Float16* agg_n   = (_Float16*)(ws + OFF_AGN);
    _Float16* kv_big  = (_Float16*)(ws + OFF_KVB);
    _Float16* kv_sm   = (_Float16*)(ws + OFF_KVS);
    _Float16* wkf = (_Float16*)(ws + OFF_WF);
    _Float16* wvf = wkf + 3 * 16384;
    _Float16* wqf = wvf + 3 * 16384;
    _Float16* waf = wqf + 2 * 16384;
    float* bke = ws + OFF_BE;
    float* bve = bke + 3 * 128;
    int* ib   = (int*)(ws + OFF_INT);
    int* cu   = ib + IO_CU;
    int* jrp  = ib + IO_JRP;
    int* bsum = ib + IO_BSUM;
    int* boff = ib + IO_BOFF;
    int* cl   = ib + IO_CL;
    const int* rp0 = jrp;
    const int* rp1 = jrp + NNEWS;
    const int* rp2 = jrp + NNEWS + NUSER;

    // ---- CSR build ----
    zero_i_kernel<<<(NTOT + 255) / 256, 256, 0, stream>>>(cu, NTOT);
    int g3e = (3 * NE + 255) / 256;
    hist3_kernel<<<g3e, 256, 0, stream>>>(ei0, ei1, ei2, cu);
    scan_part_kernel<<<NSB, 256, 0, stream>>>(cu, bsum);
    scan_top_kernel<<<1, 1024, 0, stream>>>(bsum, boff, jrp);
    scan_fin_kernel<<<NSB, 256, 0, stream>>>(cu, boff, jrp, cu);   // cu becomes cursors
    fill3_kernel<<<g3e, 256, 0, stream>>>(ei0, ei1, ei2, cu, cl);

    float* out_user = (float*)d_out;
    float* out_news = (float*)d_out + (size_t)NUSER * CH;

    for (int l = 0; l < 2; ++l) {
        const float* xu = l ? (const float*)out_user : x_user;
        const float* xn = l ? (const float*)out_news : x_news;

        eff_weights_kernel<<<6, 256, 0, stream>>>(
            Wk + (size_t)l * 2 * 16384, bk + (size_t)l * 2 * 128,
            Wv + (size_t)l * 2 * 16384, bv + (size_t)l * 2 * 128,
            a_rel + (size_t)l * 3 * 4096, m_rel + (size_t)l * 3 * 4096,
            p_rel + (size_t)l * 12, wkf, bke, wvf, bve);
        wt_convert_kernel<<<4, 256, 0, stream>>>(Wq + (size_t)l * 2 * 16384,
                                                 Wa + (size_t)l * 2 * 16384, wqf, waf);

        int gbU = (NUSER + 63) / 64, gbN = (NNEWS + 63) / 64;

        // q projections (fp16, stride 128)
        gemm_v3<1, false, false, false, true><<<gbU, 256, 0, stream>>>(
            xu, wqf, nullptr, bq + (size_t)(l * 2 + 0) * 128, nullptr,
            q_user, nullptr, 128, NUSER, nullptr, nullptr);
        gemm_v3<1, false, false, false, true><<<gbN, 256, 0, stream>>>(
            xn, wqf + 16384, nullptr, bq + (size_t)(l * 2 + 1) * 128, nullptr,
            q_news, nullptr, 128, NNEWS, nullptr, nullptr);

        // rel0 K/V (user src) -> kv_big, then news attention
        gemm_v3<2, false, false, false, true><<<gbU, 256, 0, stream>>>(
            xu, wkf, wvf, bke, bve,
            kv_big, kv_big + 128, 256, NUSER, nullptr, nullptr);
        attn_v3<<<(NNEWS + 3) / 4, 256, 0, stream>>>(
            q_news, kv_big, rp0, nullptr, nullptr, cl, agg_n, NNEWS, 0);

        // rel1 K/V (news src) -> kv_sm ; rel2 K/V (user src) -> kv_big (reuse, stream-ordered)
        gemm_v3<2, false, false, false, true><<<gbN, 256, 0, stream>>>(
            xn, wkf + 16384, wvf + 16384, bke + 128, bve + 128,
            kv_sm, kv_sm + 128, 256, NNEWS, nullptr, nullptr);
        gemm_v3<2, false, false, false, true><<<gbU, 256, 0, stream>>>(
            xu, wkf + 32768, wvf + 32768, bke + 256, bve + 256,
            kv_big, kv_big + 128, 256, NUSER, nullptr, nullptr);
        attn_v3<<<(NUSER + 3) / 4, 256, 0, stream>>>(
            q_user, kv_sm, rp1, kv_big, rp2, cl, agg_u, NUSER, 1);

        // output transform: relu(sig(skip)*(gelu(agg)@Wa + ba) + (1-sig)*x) [in-place safe]
        gemm_v3<1, true, true, true, false><<<gbU, 256, 0, stream>>>(
            agg_u, waf, nullptr, ba + (size_t)(l * 2 + 0) * 128, nullptr,
            out_user, nullptr, 128, NUSER, skip + l * 2 + 0, xu);
        gemm_v3<1, true, true, true, false><<<gbN, 256, 0, stream>>>(
            agg_n, waf + 16384, nullptr, ba + (size_t)(l * 2 + 1) * 128, nullptr,
            out_news, nullptr, 128, NNEWS, skip + l * 2 + 1, xn);
    }
    (void)in_sizes; (void)n_in; (void)out_size; (void)ws_size;
}

// Round 7
// 805.195 us; speedup vs baseline: 2.3101x; 1.0442x over previous
//
#include <hip/hip_runtime.h>
#include <cmath>

// ---------------- problem constants ----------------
constexpr int NUSER = 100000;
constexpr int NNEWS = 20000;
constexpr int CH    = 128;
constexpr int NE    = 250000;
constexpr int NTOT  = NNEWS + NUSER + NUSER;   // joint counter array (rel0|rel1|rel2)
constexpr int NSB   = (NTOT + 255) / 256;      // scan blocks = 860

typedef _Float16 f16x8 __attribute__((ext_vector_type(8)));
typedef _Float16 f16x4 __attribute__((ext_vector_type(4)));
typedef _Float16 f16x2 __attribute__((ext_vector_type(2)));
typedef float    f32x4 __attribute__((ext_vector_type(4)));

// ---------------- workspace layout (float units) ----------------
constexpr size_t OFF_QU  = 0;                                   // q_user fp16 [NUSER*128]
constexpr size_t OFF_QN  = OFF_QU  + (size_t)NUSER * 64;        // q_news fp16
constexpr size_t OFF_AGU = OFF_QN  + (size_t)NNEWS * 64;        // agg_user fp16
constexpr size_t OFF_AGN = OFF_AGU + (size_t)NUSER * 64;        // agg_news fp16
constexpr size_t OFF_KVB = OFF_AGN + (size_t)NNEWS * 64;        // kv_big fp16 [NUSER][256] (k|v interleaved)
constexpr size_t OFF_KVS = OFF_KVB + (size_t)NUSER * 128;       // kv_sm  fp16 [NNEWS][256]
constexpr size_t OFF_WF  = OFF_KVS + (size_t)NNEWS * 128;       // swizzled fp16 frags: wk[3],wv[3],wq[2],wa[2]
constexpr size_t OFF_BE  = OFF_WF  + 10 * 8192;                 // bke[3*128]+bve[3*128] f32
constexpr size_t OFF_INT = OFF_BE  + 6 * 128;
// int offsets (relative, units: int)
constexpr size_t IO_CU   = 0;                    // joint counters/cursors [NTOT]
constexpr size_t IO_JRP  = IO_CU  + NTOT;        // joint row_ptr [NTOT+1]
constexpr size_t IO_BSUM = IO_JRP + NTOT + 1;    // scan partials [NSB]
constexpr size_t IO_BOFF = IO_BSUM + NSB;        // scan offsets  [NSB]
constexpr size_t IO_CL   = IO_BOFF + NSB;        // col (global slots) [3*NE]

__device__ __forceinline__ float gelu_f(float x) {
    return 0.5f * x * (1.0f + erff(x * 0.70710678118654752440f));
}

__global__ void zero_i_kernel(int* __restrict__ p, int n) {
    int i = blockIdx.x * 256 + threadIdx.x;
    if (i < n) p[i] = 0;
}

// ---------------- CSR build (joint counter array) ----------------
__global__ void hist3_kernel(const int* __restrict__ e0, const int* __restrict__ e1,
                             const int* __restrict__ e2, int* __restrict__ cu) {
    int idx = blockIdx.x * 256 + threadIdx.x;
    if (idx >= 3 * NE) return;
    int r = idx / NE, e = idx - r * NE;
    const int* ei = (r == 0) ? e0 : (r == 1) ? e1 : e2;
    int base = (r == 0) ? 0 : (r == 1) ? NNEWS : (NNEWS + NUSER);
    atomicAdd(&cu[base + ei[NE + e]], 1);
}

__global__ __launch_bounds__(256) void scan_part_kernel(const int* __restrict__ cu,
                                                        int* __restrict__ bsum) {
    int i = blockIdx.x * 256 + threadIdx.x;
    int v = (i < NTOT) ? cu[i] : 0;
    #pragma unroll
    for (int o = 1; o < 64; o <<= 1) v += __shfl_xor(v, o);
    __shared__ int ws_[4];
    if ((threadIdx.x & 63) == 0) ws_[threadIdx.x >> 6] = v;
    __syncthreads();
    if (threadIdx.x == 0) bsum[blockIdx.x] = ws_[0] + ws_[1] + ws_[2] + ws_[3];
}

__global__ __launch_bounds__(1024) void scan_top_kernel(const int* __restrict__ bsum,
                                                        int* __restrict__ boff,
                                                        int* __restrict__ jrp) {
    __shared__ int wsum[16];
    int tid = threadIdx.x, lane = tid & 63, w = tid >> 6;
    int v = (tid < NSB) ? bsum[tid] : 0;
    int x = v;
    #pragma unroll
    for (int o = 1; o < 64; o <<= 1) { int y = __shfl_up(x, o); if (lane >= o) x += y; }
    if (lane == 63) wsum[w] = x;
    __syncthreads();
    if (tid < 16) {
        int t = wsum[tid];
        #pragma unroll
        for (int o = 1; o < 16; o <<= 1) { int y = __shfl_up(t, o); if (tid >= o) t += y; }
        wsum[tid] = t;
    }
    __syncthreads();
    int woff = w ? wsum[w - 1] : 0;
    if (tid < NSB) boff[tid] = woff + x - v;
    if (tid == 0) jrp[NTOT] = 3 * NE;
}

__global__ __launch_bounds__(256) void scan_fin_kernel(const int* __restrict__ cu,
                                                       const int* __restrict__ boff,
                                                       int* __restrict__ jrp,
                                                       int* __restrict__ cur) {
    __shared__ int wsum[4];
    int tid = threadIdx.x, lane = tid & 63, w = tid >> 6;
    int i = blockIdx.x * 256 + tid;
    int v = (i < NTOT) ? cu[i] : 0;
    int x = v;
    #pragma unroll
    for (int o = 1; o < 64; o <<= 1) { int y = __shfl_up(x, o); if (lane >= o) x += y; }
    if (lane == 63) wsum[w] = x;
    __syncthreads();
    int woff = 0;
    #pragma unroll
    for (int k = 0; k < 4; ++k) if (k < w) woff += wsum[k];
    int excl = boff[blockIdx.x] + woff + x - v;
    if (i < NTOT) { jrp[i] = excl; cur[i] = excl; }
}

__global__ void fill3_kernel(const int* __restrict__ e0, const int* __restrict__ e1,
                             const int* __restrict__ e2,
                             int* __restrict__ cur, int* __restrict__ cl) {
    int idx = blockIdx.x * 256 + threadIdx.x;
    if (idx >= 3 * NE) return;
    int r = idx / NE, e = idx - r * NE;
    const int* ei = (r == 0) ? e0 : (r == 1) ? e1 : e2;
    int base = (r == 0) ? 0 : (r == 1) ? NNEWS : (NNEWS + NUSER);
    int dst = ei[NE + e], src = ei[e];
    int p = atomicAdd(&cur[base + dst], 1);
    cl[p] = src;
}

// ---------------- swizzled-fragment dest index ----------------
// MFMA 16x16x32 fragment (lane,j): idx = lane&15, k = (lane>>4)*8 + j.
// Wf layout: [kt][ct][lane][j] contiguous -> coalesced b128 stage, conflict-free ds_read_b128.
__device__ __forceinline__ int frag_dest(int k, int col) {
    int kt = k >> 5, quad = (k >> 3) & 3, j = k & 7;
    int ct = col >> 4, m = col & 15;
    int lane = quad * 16 + m;
    return ((kt * 8 + ct) * 64 + lane) * 8 + j;
}

// ---------------- effective weights (fold a_rel/m_rel/p_rel AND log2e), swizzled fp16 ----------------
// K path scaled by p_rel/sqrt(D)*log2(e): softmax weight becomes exp2(score) = 1 v_exp_f32.
__global__ void eff_weights_kernel(const float* __restrict__ Wk, const float* __restrict__ bk,
                                   const float* __restrict__ Wv, const float* __restrict__ bv,
                                   const float* __restrict__ a_rel, const float* __restrict__ m_rel,
                                   const float* __restrict__ p_rel,
                                   _Float16* __restrict__ wkf, float* __restrict__ bke,
                                   _Float16* __restrict__ wvf, float* __restrict__ bve) {
    int b = blockIdx.x;         // 0..5
    int kind = b / 3;           // 0 = K, 1 = V
    int r = b % 3;
    const int st = (r == 1) ? 1 : 0;
    const float* W   = (kind ? Wv : Wk) + (size_t)st * 16384;
    const float* bi  = (kind ? bv : bk) + (size_t)st * 128;
    const float* rel = (kind ? m_rel : a_rel) + (size_t)r * 4096;
    _Float16* Wf = (kind ? wvf : wkf) + (size_t)r * 16384;
    float*    be = (kind ? bve : bke) + (size_t)r * 128;
    const float kscale = 0.17677669529663688f * 1.44269504088896340f;  // 1/sqrt(32)*log2(e)
    for (int o = threadIdx.x; o < 16384; o += 256) {
        int k = o >> 7, col = o & 127, h = col >> 5, e = col & 31;
        const float* wrow = W + (size_t)k * 128 + h * 32;
        const float* rcol = rel + h * 1024 + e;
        float s = 0.f;
        #pragma unroll
        for (int d = 0; d < 32; ++d) s += wrow[d] * rcol[d * 32];
        if (kind == 0) s *= p_rel[r * 4 + h] * kscale;
        Wf[frag_dest(k, col)] = (_Float16)s;
    }
    if (threadIdx.x < 128) {
        int col = threadIdx.x, h = col >> 5, e = col & 31;
        float s = 0.f;
        #pragma unroll
        for (int d = 0; d < 32; ++d) s += bi[h * 32 + d] * rel[h * 1024 + d * 32 + e];
        if (kind == 0) s *= p_rel[r * 4 + h] * kscale;
        be[col] = s;
    }
}

__global__ void wt_convert_kernel(const float* __restrict__ Wq, const float* __restrict__ Wa,
                                  _Float16* __restrict__ wqf, _Float16* __restrict__ waf) {
    int b = blockIdx.x;  // 0,1: Wq types; 2,3: Wa types
    const float* W  = (b < 2) ? (Wq + (size_t)b * 16384) : (Wa + (size_t)(b - 2) * 16384);
    _Float16*   Wf = (b < 2) ? (wqf + (size_t)b * 16384) : (waf + (size_t)(b - 2) * 16384);
    for (int o = threadIdx.x; o < 16384; o += 256) {
        int k = o >> 7, col = o & 127;
        Wf[frag_dest(k, col)] = (_Float16)W[o];
    }
}

// ---------------- MFMA GEMM v4: LDS weights + T-tile loop (amortize staging) ----------------
// Block = 4 waves. Per tile: 64 nodes (16/wave x 128 out-ch). Block covers T*64 nodes.
// mfma(A=Wfrag, B=Xfrag): D col = node (lane&15), D rows = out-ch (quad*4+reg) -> x4 stores.
template<int NOUT, bool IN_HALF, bool GELU_IN, bool SKIP_OUT, bool OUT_HALF>
__global__ __launch_bounds__(256) void gemm_v4(
    const void* __restrict__ Ain,
    const _Float16* __restrict__ Wf0, const _Float16* __restrict__ Wf1,
    const float* __restrict__ b0, const float* __restrict__ b1,
    void* __restrict__ out0, void* __restrict__ out1, int ostride,
    int N, int T, const float* __restrict__ skipv, const float* __restrict__ Xold)
{
    __shared__ _Float16 sW[NOUT * 16384];   // 32 KB per weight matrix
    const int tid = threadIdx.x;

    for (int i = tid; i < NOUT * 2048; i += 256) {
        const _Float16* src = (NOUT == 1 || i < 2048) ? (Wf0 + (size_t)i * 8)
                                                      : (Wf1 + (size_t)(i - 2048) * 8);
        *(f16x8*)(sW + (size_t)i * 8) = *(const f16x8*)src;
    }
    __syncthreads();

    const int lane = tid & 63;
    const int m = lane & 15, quad = lane >> 4, wave = tid >> 6;

    float aS = 0.f, bSk = 0.f;
    if (SKIP_OUT) {
        float sv = skipv[0];
        aS = 1.0f / (1.0f + expf(-sv));
        bSk = 1.0f - aS;
    }

    for (int t = 0; t < T; ++t) {
        const int row0 = (blockIdx.x * T + t) * 64;
        if (row0 >= N) break;                       // block-uniform (no barriers inside)
        const int node  = row0 + wave * 16 + m;
        const int nodec = (node < N) ? node : (N - 1);

        f32x4 acc0[8], acc1[8];
        #pragma unroll
        for (int u = 0; u < 8; ++u) {
            acc0[u] = (f32x4){0.f, 0.f, 0.f, 0.f};
            if (NOUT > 1) acc1[u] = (f32x4){0.f, 0.f, 0.f, 0.f};
        }

        #pragma unroll
        for (int kt = 0; kt < 4; ++kt) {
            f16x8 xf;
            if (IN_HALF) {
                xf = *(const f16x8*)((const _Float16*)Ain + (size_t)nodec * 128 + kt * 32 + quad * 8);
                if (GELU_IN) {
                    #pragma unroll
                    for (int j = 0; j < 8; ++j) xf[j] = (_Float16)gelu_f((float)xf[j]);
                }
            } else {
                const float* Af = (const float*)Ain + (size_t)nodec * 128 + kt * 32 + quad * 8;
                f32x4 a0 = *(const f32x4*)Af;
                f32x4 a1 = *(const f32x4*)(Af + 4);
                if (GELU_IN) {
                    #pragma unroll
                    for (int j = 0; j < 4; ++j) { a0[j] = gelu_f(a0[j]); a1[j] = gelu_f(a1[j]); }
                }
                xf = (f16x8){(_Float16)a0[0], (_Float16)a0[1], (_Float16)a0[2], (_Float16)a0[3],
                             (_Float16)a1[0], (_Float16)a1[1], (_Float16)a1[2], (_Float16)a1[3]};
            }
            #pragma unroll
            for (int ct = 0; ct < 8; ++ct) {
                f16x8 wf0 = *(const f16x8*)(sW + ((kt * 8 + ct) * 64 + lane) * 8);
                acc0[ct] = __builtin_amdgcn_mfma_f32_16x16x32_f16(wf0, xf, acc0[ct], 0, 0, 0);
                if (NOUT > 1) {
                    f16x8 wf1 = *(const f16x8*)(sW + 16384 + ((kt * 8 + ct) * 64 + lane) * 8);
                    acc1[ct] = __builtin_amdgcn_mfma_f32_16x16x32_f16(wf1, xf, acc1[ct], 0, 0, 0);
                }
            }
        }

        if (node >= N) continue;

        #pragma unroll
        for (int ct = 0; ct < 8; ++ct) {
            int c = ct * 16 + quad * 4;      // out-channel base for this lane's 4 regs
            {
                f32x4 r = acc0[ct] + *(const f32x4*)(b0 + c);
                if (SKIP_OUT) {
                    f32x4 xo = *(const f32x4*)(Xold + (size_t)node * 128 + c);
                    #pragma unroll
                    for (int j = 0; j < 4; ++j) r[j] = fmaxf(aS * r[j] + bSk * xo[j], 0.f);
                }
                if (OUT_HALF) {
                    f16x4 h = {(_Float16)r[0], (_Float16)r[1], (_Float16)r[2], (_Float16)r[3]};
                    *(f16x4*)((_Float16*)out0 + (size_t)node * ostride + c) = h;
                } else {
                    *(f32x4*)((float*)out0 + (size_t)node * ostride + c) = r;
                }
            }
            if (NOUT > 1) {
                f32x4 r = acc1[ct] + *(const f32x4*)(b1 + c);
                f16x4 h = {(_Float16)r[0], (_Float16)r[1], (_Float16)r[2], (_Float16)r[3]};
                *(f16x4*)((_Float16*)out1 + (size_t)node * ostride + c) = h;
            }
        }
    }
}

// ---------------- attention v4: 4 nodes/wave (16 lanes/node), serial edges ----------------
// kv interleaved [node][k0..k127 | v0..v127] fp16. Lane sub (0..15): channels sub*8..+7,
// head = sub>>2 (4 lanes/head). No cross-edge-group combine; w = exp2(score) (log2e folded).
__global__ __launch_bounds__(256) void attn_v4(
    const _Float16* __restrict__ q,
    const _Float16* __restrict__ kv1, const int* __restrict__ rp1,
    const _Float16* __restrict__ kv2, const int* __restrict__ rp2,
    const int* __restrict__ cl,
    _Float16* __restrict__ agg, int Ndst, int two)
{
    int d = blockIdx.x * 16 + (threadIdx.x >> 4);   // 16 nodes per block (4 per wave)
    if (d >= Ndst) return;
    const int sub = threadIdx.x & 15;
    f16x8 qh = *(const f16x8*)(q + (size_t)d * 128 + sub * 8);
    float acc[8] = {0.f, 0.f, 0.f, 0.f, 0.f, 0.f, 0.f, 0.f};

    for (int rel = 0; rel < 1 + two; ++rel) {
        const _Float16* kv = rel ? kv2 : kv1;
        const int* rp = rel ? rp2 : rp1;
        int e0 = rp[d], e1 = rp[d + 1];
        float den = 0.f;
        float s[8] = {0.f, 0.f, 0.f, 0.f, 0.f, 0.f, 0.f, 0.f};
        for (int e = e0; e < e1; ++e) {
            int src = cl[e];
            const _Float16* row = kv + (size_t)src * 256;
            f16x8 kk = *(const f16x8*)(row + sub * 8);
            f16x8 vv = *(const f16x8*)(row + 128 + sub * 8);
            float p = 0.f;
#if __has_builtin(__builtin_amdgcn_fdot2)
            const f16x2* kp = (const f16x2*)&kk;
            const f16x2* qp = (const f16x2*)&qh;
            p = __builtin_amdgcn_fdot2(kp[0], qp[0], p, false);
            p = __builtin_amdgcn_fdot2(kp[1], qp[1], p, false);
            p = __builtin_amdgcn_fdot2(kp[2], qp[2], p, false);
            p = __builtin_amdgcn_fdot2(kp[3], qp[3], p, false);
#else
            #pragma unroll
            for (int j = 0; j < 8; ++j) p += (float)kk[j] * (float)qh[j];
#endif
            p += __shfl_xor(p, 1);
            p += __shfl_xor(p, 2);       // 4 lanes/head -> full 32-ch head dot
            float w = exp2f(p);          // log2e folded into k_eff: single v_exp_f32
            den += w;
            #pragma unroll
            for (int j = 0; j < 8; ++j) s[j] += w * (float)vv[j];
        }
        if (den > 0.f) {
            float inv = 1.f / den;
            #pragma unroll
            for (int j = 0; j < 8; ++j) acc[j] += s[j] * inv;
        }
    }

    f16x8 o;
    #pragma unroll
    for (int j = 0; j < 8; ++j) o[j] = (_Float16)acc[j];
    *(f16x8*)(agg + (size_t)d * 128 + sub * 8) = o;
}

// ---------------- orchestration ----------------
extern "C" void kernel_launch(void* const* d_in, const int* in_sizes, int n_in,
                              void* d_out, int out_size, void* d_ws, size_t ws_size,
                              hipStream_t stream)
{
    const float* x_user = (const float*)d_in[0];
    const float* x_news = (const float*)d_in[1];
    const int* ei0 = (const int*)d_in[2];
    const int* ei1 = (const int*)d_in[3];
    const int* ei2 = (const int*)d_in[4];
    const float* Wk = (const float*)d_in[5];
    const float* bk = (const float*)d_in[6];
    const float* Wq = (const float*)d_in[7];
    const float* bq = (const float*)d_in[8];
    const float* Wv = (const float*)d_in[9];
    const float* bv = (const float*)d_in[10];
    const float* Wa = (const float*)d_in[11];
    const float* ba = (const float*)d_in[12];
    const float* skip = (const float*)d_in[13];
    const float* a_rel = (const float*)d_in[14];
    const float* m_rel = (const float*)d_in[15];
    const float* p_rel = (const float*)d_in[16];

    float* ws = (float*)d_ws;
    _Float16* q_user  = (_Float16*)(ws + OFF_QU);
    _Float16* q_news  = (_Float16*)(ws + OFF_QN);
    _Float16* agg_u   = (_Float16*)(ws + OFF_AGU);
    _Float16* agg_n   = (_Float16*)(ws + OFF_AGN);
    _Float16* kv_big  = (_Float16*)(ws + OFF_KVB);
    _Float16* kv_sm   = (_Float16*)(ws + OFF_KVS);
    _Float16* wkf = (_Float16*)(ws + OFF_WF);
    _Float16* wvf = wkf + 3 * 16384;
    _Float16* wqf = wvf + 3 * 16384;
    _Float16* waf = wqf + 2 * 16384;
    float* bke = ws + OFF_BE;
    float* bve = bke + 3 * 128;
    int* ib   = (int*)(ws + OFF_INT);
    int* cu   = ib + IO_CU;
    int* jrp  = ib + IO_JRP;
    int* bsum = ib + IO_BSUM;
    int* boff = ib + IO_BOFF;
    int* cl   = ib + IO_CL;
    const int* rp0 = jrp;
    const int* rp1 = jrp + NNEWS;
    const int* rp2 = jrp + NNEWS + NUSER;

    // ---- CSR build ----
    zero_i_kernel<<<(NTOT + 255) / 256, 256, 0, stream>>>(cu, NTOT);
    int g3e = (3 * NE + 255) / 256;
    hist3_kernel<<<g3e, 256, 0, stream>>>(ei0, ei1, ei2, cu);
    scan_part_kernel<<<NSB, 256, 0, stream>>>(cu, bsum);
    scan_top_kernel<<<1, 1024, 0, stream>>>(bsum, boff, jrp);
    scan_fin_kernel<<<NSB, 256, 0, stream>>>(cu, boff, jrp, cu);   // cu becomes cursors
    fill3_kernel<<<g3e, 256, 0, stream>>>(ei0, ei1, ei2, cu, cl);

    float* out_user = (float*)d_out;
    float* out_news = (float*)d_out + (size_t)NUSER * CH;

    constexpr int TU = 4;                         // tiles/block for user-sized GEMMs
    int gbU = (NUSER + 64 * TU - 1) / (64 * TU);
    int gbN = (NNEWS + 63) / 64;                  // news: T=1 (keep TLP)

    for (int l = 0; l < 2; ++l) {
        const float* xu = l ? (const float*)out_user : x_user;
        const float* xn = l ? (const float*)out_news : x_news;

        eff_weights_kernel<<<6, 256, 0, stream>>>(
            Wk + (size_t)l * 2 * 16384, bk + (size_t)l * 2 * 128,
            Wv + (size_t)l * 2 * 16384, bv + (size_t)l * 2 * 128,
            a_rel + (size_t)l * 3 * 4096, m_rel + (size_t)l * 3 * 4096,
            p_rel + (size_t)l * 12, wkf, bke, wvf, bve);
        wt_convert_kernel<<<4, 256, 0, stream>>>(Wq + (size_t)l * 2 * 16384,
                                                 Wa + (size_t)l * 2 * 16384, wqf, waf);

        // q projections (fp16, stride 128)
        gemm_v4<1, false, false, false, true><<<gbU, 256, 0, stream>>>(
            xu, wqf, nullptr, bq + (size_t)(l * 2 + 0) * 128, nullptr,
            q_user, nullptr, 128, NUSER, TU, nullptr, nullptr);
        gemm_v4<1, false, false, false, true><<<gbN, 256, 0, stream>>>(
            xn, wqf + 16384, nullptr, bq + (size_t)(l * 2 + 1) * 128, nullptr,
            q_news, nullptr, 128, NNEWS, 1, nullptr, nullptr);

        // rel0 K/V (user src) -> kv_big, then news attention
        gemm_v4<2, false, false, false, true><<<gbU, 256, 0, stream>>>(
            xu, wkf, wvf, bke, bve,
            kv_big, kv_big + 128, 256, NUSER, TU, nullptr, nullptr);
        attn_v4<<<(NNEWS + 15) / 16, 256, 0, stream>>>(
            q_news, kv_big, rp0, nullptr, nullptr, cl, agg_n, NNEWS, 0);

        // rel1 K/V (news src) -> kv_sm ; rel2 K/V (user src) -> kv_big (reuse, stream-ordered)
        gemm_v4<2, false, false, false, true><<<gbN, 256, 0, stream>>>(
            xn, wkf + 16384, wvf + 16384, bke + 128, bve + 128,
            kv_sm, kv_sm + 128, 256, NNEWS, 1, nullptr, nullptr);
        gemm_v4<2, false, false, false, true><<<gbU, 256, 0, stream>>>(
            xu, wkf + 32768, wvf + 32768, bke + 256, bve + 256,
            kv_big, kv_big + 128, 256, NUSER, TU, nullptr, nullptr);
        attn_v4<<<(NUSER + 15) / 16, 256, 0, stream>>>(
            q_user, kv_sm, rp1, kv_big, rp2, cl, agg_u, NUSER, 1);

        // output transform: relu(sig(skip)*(gelu(agg)@Wa + ba) + (1-sig)*x) [in-place safe]
        gemm_v4<1, true, true, true, false><<<gbU, 256, 0, stream>>>(
            agg_u, waf, nullptr, ba + (size_t)(l * 2 + 0) * 128, nullptr,
            out_user, nullptr, 128, NUSER, TU, skip + l * 2 + 0, xu);
        gemm_v4<1, true, true, true, false><<<gbN, 256, 0, stream>>>(
            agg_n, waf + 16384, nullptr, ba + (size_t)(l * 2 + 1) * 128, nullptr,
            out_news, nullptr, 128, NNEWS, 1, skip + l * 2 + 1, xn);
    }
    (void)in_sizes; (void)n_in; (void)out_size; (void)ws_size;
}

// Round 8
// 682.773 us; speedup vs baseline: 2.7244x; 1.1793x over previous
//
#include <hip/hip_runtime.h>
#include <cmath>

// ---------------- problem constants ----------------
constexpr int NUSER = 100000;
constexpr int NNEWS = 20000;
constexpr int CH    = 128;
constexpr int NE    = 250000;
constexpr int NTOT  = NNEWS + NUSER + NUSER;   // joint counter array (rel0|rel1|rel2)
constexpr int NSB   = (NTOT + 255) / 256;      // scan blocks = 860

typedef _Float16 f16x8 __attribute__((ext_vector_type(8)));
typedef _Float16 f16x4 __attribute__((ext_vector_type(4)));
typedef _Float16 f16x2 __attribute__((ext_vector_type(2)));
typedef float    f32x4 __attribute__((ext_vector_type(4)));

// ---------------- workspace layout (float units) ----------------
constexpr size_t OFF_QU  = 0;                                   // q_user fp16 [NUSER*128]
constexpr size_t OFF_QN  = OFF_QU  + (size_t)NUSER * 64;        // q_news fp16
constexpr size_t OFF_AGU = OFF_QN  + (size_t)NNEWS * 64;        // agg_user fp16
constexpr size_t OFF_AGN = OFF_AGU + (size_t)NUSER * 64;        // agg_news fp16
constexpr size_t OFF_KVB = OFF_AGN + (size_t)NNEWS * 64;        // kv_big fp16 [NUSER][256] (k|v interleaved)
constexpr size_t OFF_KVS = OFF_KVB + (size_t)NUSER * 128;       // kv_sm  fp16 [NNEWS][256]
constexpr size_t OFF_WF  = OFF_KVS + (size_t)NNEWS * 128;       // swizzled fp16 frags, BOTH layers:
                                                                //   wkf[2][3], wvf[2][3], wqf[2][2], waf[2][2] = 20 matrices
constexpr size_t OFF_BE  = OFF_WF  + 20 * 8192;                 // bke[2][3][128] + bve[2][3][128] f32
constexpr size_t OFF_INT = OFF_BE  + 2 * 768;
// int offsets (relative, units: int)
constexpr size_t IO_CU   = 0;                    // joint counters/cursors [NTOT]
constexpr size_t IO_JRP  = IO_CU  + NTOT;        // joint row_ptr [NTOT+1]
constexpr size_t IO_BSUM = IO_JRP + NTOT + 1;    // scan partials [NSB]
constexpr size_t IO_BOFF = IO_BSUM + NSB;        // scan offsets  [NSB]
constexpr size_t IO_CL   = IO_BOFF + NSB;        // col (global slots) [3*NE]

__device__ __forceinline__ float gelu_f(float x) {
    return 0.5f * x * (1.0f + erff(x * 0.70710678118654752440f));
}

__global__ void zero_i_kernel(int* __restrict__ p, int n) {
    int i = blockIdx.x * 256 + threadIdx.x;
    if (i < n) p[i] = 0;
}

// ---------------- CSR build (joint counter array) ----------------
__global__ void hist3_kernel(const int* __restrict__ e0, const int* __restrict__ e1,
                             const int* __restrict__ e2, int* __restrict__ cu) {
    int idx = blockIdx.x * 256 + threadIdx.x;
    if (idx >= 3 * NE) return;
    int r = idx / NE, e = idx - r * NE;
    const int* ei = (r == 0) ? e0 : (r == 1) ? e1 : e2;
    int base = (r == 0) ? 0 : (r == 1) ? NNEWS : (NNEWS + NUSER);
    atomicAdd(&cu[base + ei[NE + e]], 1);
}

__global__ __launch_bounds__(256) void scan_part_kernel(const int* __restrict__ cu,
                                                        int* __restrict__ bsum) {
    int i = blockIdx.x * 256 + threadIdx.x;
    int v = (i < NTOT) ? cu[i] : 0;
    #pragma unroll
    for (int o = 1; o < 64; o <<= 1) v += __shfl_xor(v, o);
    __shared__ int ws_[4];
    if ((threadIdx.x & 63) == 0) ws_[threadIdx.x >> 6] = v;
    __syncthreads();
    if (threadIdx.x == 0) bsum[blockIdx.x] = ws_[0] + ws_[1] + ws_[2] + ws_[3];
}

__global__ __launch_bounds__(1024) void scan_top_kernel(const int* __restrict__ bsum,
                                                        int* __restrict__ boff,
                                                        int* __restrict__ jrp) {
    __shared__ int wsum[16];
    int tid = threadIdx.x, lane = tid & 63, w = tid >> 6;
    int v = (tid < NSB) ? bsum[tid] : 0;
    int x = v;
    #pragma unroll
    for (int o = 1; o < 64; o <<= 1) { int y = __shfl_up(x, o); if (lane >= o) x += y; }
    if (lane == 63) wsum[w] = x;
    __syncthreads();
    if (tid < 16) {
        int t = wsum[tid];
        #pragma unroll
        for (int o = 1; o < 16; o <<= 1) { int y = __shfl_up(t, o); if (tid >= o) t += y; }
        wsum[tid] = t;
    }
    __syncthreads();
    int woff = w ? wsum[w - 1] : 0;
    if (tid < NSB) boff[tid] = woff + x - v;
    if (tid == 0) jrp[NTOT] = 3 * NE;
}

__global__ __launch_bounds__(256) void scan_fin_kernel(const int* __restrict__ cu,
                                                       const int* __restrict__ boff,
                                                       int* __restrict__ jrp,
                                                       int* __restrict__ cur) {
    __shared__ int wsum[4];
    int tid = threadIdx.x, lane = tid & 63, w = tid >> 6;
    int i = blockIdx.x * 256 + tid;
    int v = (i < NTOT) ? cu[i] : 0;
    int x = v;
    #pragma unroll
    for (int o = 1; o < 64; o <<= 1) { int y = __shfl_up(x, o); if (lane >= o) x += y; }
    if (lane == 63) wsum[w] = x;
    __syncthreads();
    int woff = 0;
    #pragma unroll
    for (int k = 0; k < 4; ++k) if (k < w) woff += wsum[k];
    int excl = boff[blockIdx.x] + woff + x - v;
    if (i < NTOT) { jrp[i] = excl; cur[i] = excl; }
}

__global__ void fill3_kernel(const int* __restrict__ e0, const int* __restrict__ e1,
                             const int* __restrict__ e2,
                             int* __restrict__ cur, int* __restrict__ cl) {
    int idx = blockIdx.x * 256 + threadIdx.x;
    if (idx >= 3 * NE) return;
    int r = idx / NE, e = idx - r * NE;
    const int* ei = (r == 0) ? e0 : (r == 1) ? e1 : e2;
    int base = (r == 0) ? 0 : (r == 1) ? NNEWS : (NNEWS + NUSER);
    int dst = ei[NE + e], src = ei[e];
    int p = atomicAdd(&cur[base + dst], 1);
    cl[p] = src;
}

// ---------------- swizzled-fragment dest index ----------------
// MFMA 16x16x32 fragment (lane,j): idx = lane&15, k = (lane>>4)*8 + j.
// Wf layout: [kt][ct][lane][j] contiguous -> coalesced b128 stage, conflict-free ds_read_b128.
__device__ __forceinline__ int frag_dest(int k, int col) {
    int kt = k >> 5, quad = (k >> 3) & 3, j = k & 7;
    int ct = col >> 4, m = col & 15;
    int lane = quad * 16 + m;
    return ((kt * 8 + ct) * 64 + lane) * 8 + j;
}

// ---------------- ONE flat weight-prep kernel: both layers, all matrices ----------------
// R7 post-mortem: eff_weights was a 6-block launch = 54 us of near-idle GPU, twice.
// Items: eff K/V fold (2l x 2kind x 3r x 16384), converts (2l x 4 x 16384), biases.
// K path folds p_rel/sqrt(D)*log2(e) -> softmax weight is a single exp2.
constexpr int NEFF = 2 * 2 * 3 * 16384;   // 196608
constexpr int NCVT = 2 * 4 * 16384;       // 131072
constexpr int NBIA = 2 * 2 * 3 * 128;     // 1536
constexpr int NPREP = NEFF + NCVT + NBIA;

__global__ __launch_bounds__(256) void prep_weights_kernel(
    const float* __restrict__ Wk, const float* __restrict__ bk,
    const float* __restrict__ Wv, const float* __restrict__ bv,
    const float* __restrict__ Wq, const float* __restrict__ Wa,
    const float* __restrict__ a_rel, const float* __restrict__ m_rel,
    const float* __restrict__ p_rel,
    _Float16* __restrict__ wkf, float* __restrict__ bke,
    _Float16* __restrict__ wvf, float* __restrict__ bve,
    _Float16* __restrict__ wqf, _Float16* __restrict__ waf)
{
    const float kscale = 0.17677669529663688f * 1.44269504088896340f;  // 1/sqrt(32)*log2(e)
    int idx = blockIdx.x * 256 + threadIdx.x;
    if (idx < NEFF) {
        int o = idx & 16383;
        int g = idx >> 14;          // (l*2+kind)*3 + r
        int r = g % 3, lk = g / 3, kind = lk & 1, l = lk >> 1;
        int st = (r == 1) ? 1 : 0;
        const float* W   = (kind ? Wv : Wk) + ((size_t)(l * 2 + st)) * 16384;
        const float* rel = (kind ? m_rel : a_rel) + ((size_t)(l * 3 + r)) * 4096;
        _Float16* Wf = (kind ? wvf : wkf) + ((size_t)(l * 3 + r)) * 16384;
        int k = o >> 7, col = o & 127, h = col >> 5, e = col & 31;
        const float* wrow = W + (size_t)k * 128 + h * 32;
        const float* rcol = rel + h * 1024 + e;
        float s = 0.f;
        #pragma unroll
        for (int d = 0; d < 32; ++d) s += wrow[d] * rcol[d * 32];
        if (kind == 0) s *= p_rel[(l * 3 + r) * 4 + h] * kscale;
        Wf[frag_dest(k, col)] = (_Float16)s;
    } else if (idx < NEFF + NCVT) {
        int t = idx - NEFF;
        int o = t & 16383;
        int b = t >> 14;            // l*4 + sub  (sub 0,1: Wq types; 2,3: Wa types)
        int l = b >> 2, sub = b & 3;
        const float* W;
        _Float16* Wf;
        if (sub < 2) { W = Wq + ((size_t)(l * 2 + sub)) * 16384;     Wf = wqf + ((size_t)(l * 2 + sub)) * 16384; }
        else         { W = Wa + ((size_t)(l * 2 + sub - 2)) * 16384; Wf = waf + ((size_t)(l * 2 + sub - 2)) * 16384; }
        int k = o >> 7, col = o & 127;
        Wf[frag_dest(k, col)] = (_Float16)W[o];
    } else if (idx < NPREP) {
        int t = idx - NEFF - NCVT;
        int col = t & 127;
        int g = t >> 7;             // (l*2+kind)*3 + r
        int r = g % 3, lk = g / 3, kind = lk & 1, l = lk >> 1;
        int st = (r == 1) ? 1 : 0;
        const float* bi  = (kind ? bv : bk) + ((size_t)(l * 2 + st)) * 128;
        const float* rel = (kind ? m_rel : a_rel) + ((size_t)(l * 3 + r)) * 4096;
        float* be = (kind ? bve : bke) + (size_t)l * 384 + r * 128;
        int h = col >> 5, e = col & 31;
        float s = 0.f;
        #pragma unroll
        for (int d = 0; d < 32; ++d) s += bi[h * 32 + d] * rel[h * 1024 + d * 32 + e];
        if (kind == 0) s *= p_rel[(l * 3 + r) * 4 + h] * kscale;
        be[col] = s;
    }
}

// ---------------- MFMA GEMM v4: LDS weights + T-tile loop (amortize staging) ----------------
// Block = 4 waves. Per tile: 64 nodes (16/wave x 128 out-ch). Block covers T*64 nodes.
// mfma(A=Wfrag, B=Xfrag): D col = node (lane&15), D rows = out-ch (quad*4+reg) -> x4 stores.
template<int NOUT, bool IN_HALF, bool GELU_IN, bool SKIP_OUT, bool OUT_HALF>
__global__ __launch_bounds__(256) void gemm_v4(
    const void* __restrict__ Ain,
    const _Float16* __restrict__ Wf0, const _Float16* __restrict__ Wf1,
    const float* __restrict__ b0, const float* __restrict__ b1,
    void* __restrict__ out0, void* __restrict__ out1, int ostride,
    int N, int T, const float* __restrict__ skipv, const float* __restrict__ Xold)
{
    __shared__ _Float16 sW[NOUT * 16384];   // 32 KB per weight matrix
    const int tid = threadIdx.x;

    for (int i = tid; i < NOUT * 2048; i += 256) {
        const _Float16* src = (NOUT == 1 || i < 2048) ? (Wf0 + (size_t)i * 8)
                                                      : (Wf1 + (size_t)(i - 2048) * 8);
        *(f16x8*)(sW + (size_t)i * 8) = *(const f16x8*)src;
    }
    __syncthreads();

    const int lane = tid & 63;
    const int m = lane & 15, quad = lane >> 4, wave = tid >> 6;

    float aS = 0.f, bSk = 0.f;
    if (SKIP_OUT) {
        float sv = skipv[0];
        aS = 1.0f / (1.0f + expf(-sv));
        bSk = 1.0f - aS;
    }

    for (int t = 0; t < T; ++t) {
        const int row0 = (blockIdx.x * T + t) * 64;
        if (row0 >= N) break;                       // block-uniform (no barriers inside)
        const int node  = row0 + wave * 16 + m;
        const int nodec = (node < N) ? node : (N - 1);

        f32x4 acc0[8], acc1[8];
        #pragma unroll
        for (int u = 0; u < 8; ++u) {
            acc0[u] = (f32x4){0.f, 0.f, 0.f, 0.f};
            if (NOUT > 1) acc1[u] = (f32x4){0.f, 0.f, 0.f, 0.f};
        }

        #pragma unroll
        for (int kt = 0; kt < 4; ++kt) {
            f16x8 xf;
            if (IN_HALF) {
                xf = *(const f16x8*)((const _Float16*)Ain + (size_t)nodec * 128 + kt * 32 + quad * 8);
                if (GELU_IN) {
                    #pragma unroll
                    for (int j = 0; j < 8; ++j) xf[j] = (_Float16)gelu_f((float)xf[j]);
                }
            } else {
                const float* Af = (const float*)Ain + (size_t)nodec * 128 + kt * 32 + quad * 8;
                f32x4 a0 = *(const f32x4*)Af;
                f32x4 a1 = *(const f32x4*)(Af + 4);
                if (GELU_IN) {
                    #pragma unroll
                    for (int j = 0; j < 4; ++j) { a0[j] = gelu_f(a0[j]); a1[j] = gelu_f(a1[j]); }
                }
                xf = (f16x8){(_Float16)a0[0], (_Float16)a0[1], (_Float16)a0[2], (_Float16)a0[3],
                             (_Float16)a1[0], (_Float16)a1[1], (_Float16)a1[2], (_Float16)a1[3]};
            }
            #pragma unroll
            for (int ct = 0; ct < 8; ++ct) {
                f16x8 wf0 = *(const f16x8*)(sW + ((kt * 8 + ct) * 64 + lane) * 8);
                acc0[ct] = __builtin_amdgcn_mfma_f32_16x16x32_f16(wf0, xf, acc0[ct], 0, 0, 0);
                if (NOUT > 1) {
                    f16x8 wf1 = *(const f16x8*)(sW + 16384 + ((kt * 8 + ct) * 64 + lane) * 8);
                    acc1[ct] = __builtin_amdgcn_mfma_f32_16x16x32_f16(wf1, xf, acc1[ct], 0, 0, 0);
                }
            }
        }

        if (node >= N) continue;

        #pragma unroll
        for (int ct = 0; ct < 8; ++ct) {
            int c = ct * 16 + quad * 4;      // out-channel base for this lane's 4 regs
            {
                f32x4 r = acc0[ct] + *(const f32x4*)(b0 + c);
                if (SKIP_OUT) {
                    f32x4 xo = *(const f32x4*)(Xold + (size_t)node * 128 + c);
                    #pragma unroll
                    for (int j = 0; j < 4; ++j) r[j] = fmaxf(aS * r[j] + bSk * xo[j], 0.f);
                }
                if (OUT_HALF) {
                    f16x4 h = {(_Float16)r[0], (_Float16)r[1], (_Float16)r[2], (_Float16)r[3]};
                    *(f16x4*)((_Float16*)out0 + (size_t)node * ostride + c) = h;
                } else {
                    *(f32x4*)((float*)out0 + (size_t)node * ostride + c) = r;
                }
            }
            if (NOUT > 1) {
                f32x4 r = acc1[ct] + *(const f32x4*)(b1 + c);
                f16x4 h = {(_Float16)r[0], (_Float16)r[1], (_Float16)r[2], (_Float16)r[3]};
                *(f16x4*)((_Float16*)out1 + (size_t)node * ostride + c) = h;
            }
        }
    }
}

// ---------------- attention v4: 4 nodes/wave (16 lanes/node), serial edges ----------------
// kv interleaved [node][k0..k127 | v0..v127] fp16. Lane sub (0..15): channels sub*8..+7,
// head = sub>>2 (4 lanes/head). w = exp2(score) (log2e folded into k_eff).
__global__ __launch_bounds__(256) void attn_v4(
    const _Float16* __restrict__ q,
    const _Float16* __restrict__ kv1, const int* __restrict__ rp1,
    const _Float16* __restrict__ kv2, const int* __restrict__ rp2,
    const int* __restrict__ cl,
    _Float16* __restrict__ agg, int Ndst, int two)
{
    int d = blockIdx.x * 16 + (threadIdx.x >> 4);   // 16 nodes per block (4 per wave)
    if (d >= Ndst) return;
    const int sub = threadIdx.x & 15;
    f16x8 qh = *(const f16x8*)(q + (size_t)d * 128 + sub * 8);
    float acc[8] = {0.f, 0.f, 0.f, 0.f, 0.f, 0.f, 0.f, 0.f};

    for (int rel = 0; rel < 1 + two; ++rel) {
        const _Float16* kv = rel ? kv2 : kv1;
        const int* rp = rel ? rp2 : rp1;
        int e0 = rp[d], e1 = rp[d + 1];
        float den = 0.f;
        float s[8] = {0.f, 0.f, 0.f, 0.f, 0.f, 0.f, 0.f, 0.f};
        for (int e = e0; e < e1; ++e) {
            int src = cl[e];
            const _Float16* row = kv + (size_t)src * 256;
            f16x8 kk = *(const f16x8*)(row + sub * 8);
            f16x8 vv = *(const f16x8*)(row + 128 + sub * 8);
            float p = 0.f;
#if __has_builtin(__builtin_amdgcn_fdot2)
            const f16x2* kp = (const f16x2*)&kk;
            const f16x2* qp = (const f16x2*)&qh;
            p = __builtin_amdgcn_fdot2(kp[0], qp[0], p, false);
            p = __builtin_amdgcn_fdot2(kp[1], qp[1], p, false);
            p = __builtin_amdgcn_fdot2(kp[2], qp[2], p, false);
            p = __builtin_amdgcn_fdot2(kp[3], qp[3], p, false);
#else
            #pragma unroll
            for (int j = 0; j < 8; ++j) p += (float)kk[j] * (float)qh[j];
#endif
            p += __shfl_xor(p, 1);
            p += __shfl_xor(p, 2);       // 4 lanes/head -> full 32-ch head dot
            float w = exp2f(p);
            den += w;
            #pragma unroll
            for (int j = 0; j < 8; ++j) s[j] += w * (float)vv[j];
        }
        if (den > 0.f) {
            float inv = 1.f / den;
            #pragma unroll
            for (int j = 0; j < 8; ++j) acc[j] += s[j] * inv;
        }
    }

    f16x8 o;
    #pragma unroll
    for (int j = 0; j < 8; ++j) o[j] = (_Float16)acc[j];
    *(f16x8*)(agg + (size_t)d * 128 + sub * 8) = o;
}

// ---------------- orchestration ----------------
extern "C" void kernel_launch(void* const* d_in, const int* in_sizes, int n_in,
                              void* d_out, int out_size, void* d_ws, size_t ws_size,
                              hipStream_t stream)
{
    const float* x_user = (const float*)d_in[0];
    const float* x_news = (const float*)d_in[1];
    const int* ei0 = (const int*)d_in[2];
    const int* ei1 = (const int*)d_in[3];
    const int* ei2 = (const int*)d_in[4];
    const float* Wk = (const float*)d_in[5];
    const float* bk = (const float*)d_in[6];
    const float* Wq = (const float*)d_in[7];
    const float* bq = (const float*)d_in[8];
    const float* Wv = (const float*)d_in[9];
    const float* bv = (const float*)d_in[10];
    const float* Wa = (const float*)d_in[11];
    const float* ba = (const float*)d_in[12];
    const float* skip = (const float*)d_in[13];
    const float* a_rel = (const float*)d_in[14];
    const float* m_rel = (const float*)d_in[15];
    const float* p_rel = (const float*)d_in[16];

    float* ws = (float*)d_ws;
    _Float16* q_user  = (_Float16*)(ws + OFF_QU);
    _Float16* q_news  = (_Float16*)(ws + OFF_QN);
    _Float16* agg_u   = (_Float16*)(ws + OFF_AGU);
    _Float16* agg_n   = (_Float16*)(ws + OFF_AGN);
    _Float16* kv_big  = (_Float16*)(ws + OFF_KVB);
    _Float16* kv_sm   = (_Float16*)(ws + OFF_KVS);
    _Float16* wkf = (_Float16*)(ws + OFF_WF);       // [2][3] matrices
    _Float16* wvf = wkf + 6 * 16384;                // [2][3]
    _Float16* wqf = wvf + 6 * 16384;                // [2][2]
    _Float16* waf = wqf + 4 * 16384;                // [2][2]
    float* bke = ws + OFF_BE;                       // [2][3][128]
    float* bve = bke + 768;
    int* ib   = (int*)(ws + OFF_INT);
    int* cu   = ib + IO_CU;
    int* jrp  = ib + IO_JRP;
    int* bsum = ib + IO_BSUM;
    int* boff = ib + IO_BOFF;
    int* cl   = ib + IO_CL;
    const int* rp0 = jrp;
    const int* rp1 = jrp + NNEWS;
    const int* rp2 = jrp + NNEWS + NUSER;

    // ---- weight prep (both layers, one flat dispatch) ----
    prep_weights_kernel<<<(NPREP + 255) / 256, 256, 0, stream>>>(
        Wk, bk, Wv, bv, Wq, Wa, a_rel, m_rel, p_rel,
        wkf, bke, wvf, bve, wqf, waf);

    // ---- CSR build ----
    zero_i_kernel<<<(NTOT + 255) / 256, 256, 0, stream>>>(cu, NTOT);
    int g3e = (3 * NE + 255) / 256;
    hist3_kernel<<<g3e, 256, 0, stream>>>(ei0, ei1, ei2, cu);
    scan_part_kernel<<<NSB, 256, 0, stream>>>(cu, bsum);
    scan_top_kernel<<<1, 1024, 0, stream>>>(bsum, boff, jrp);
    scan_fin_kernel<<<NSB, 256, 0, stream>>>(cu, boff, jrp, cu);   // cu becomes cursors
    fill3_kernel<<<g3e, 256, 0, stream>>>(ei0, ei1, ei2, cu, cl);

    float* out_user = (float*)d_out;
    float* out_news = (float*)d_out + (size_t)NUSER * CH;

    constexpr int TU = 4;                         // tiles/block for user-sized GEMMs
    int gbU = (NUSER + 64 * TU - 1) / (64 * TU);
    int gbN = (NNEWS + 63) / 64;                  // news: T=1 (keep TLP)

    for (int l = 0; l < 2; ++l) {
        const float* xu = l ? (const float*)out_user : x_user;
        const float* xn = l ? (const float*)out_news : x_news;
        _Float16* wkf_l = wkf + (size_t)l * 3 * 16384;
        _Float16* wvf_l = wvf + (size_t)l * 3 * 16384;
        _Float16* wqf_l = wqf + (size_t)l * 2 * 16384;
        _Float16* waf_l = waf + (size_t)l * 2 * 16384;
        float* bke_l = bke + (size_t)l * 384;
        float* bve_l = bve + (size_t)l * 384;

        // q projections (fp16, stride 128)
        gemm_v4<1, false, false, false, true><<<gbU, 256, 0, stream>>>(
            xu, wqf_l, nullptr, bq + (size_t)(l * 2 + 0) * 128, nullptr,
            q_user, nullptr, 128, NUSER, TU, nullptr, nullptr);
        gemm_v4<1, false, false, false, true><<<gbN, 256, 0, stream>>>(
            xn, wqf_l + 16384, nullptr, bq + (size_t)(l * 2 + 1) * 128, nullptr,
            q_news, nullptr, 128, NNEWS, 1, nullptr, nullptr);

        // rel0 K/V (user src) -> kv_big, then news attention
        gemm_v4<2, false, false, false, true><<<gbU, 256, 0, stream>>>(
            xu, wkf_l, wvf_l, bke_l, bve_l,
            kv_big, kv_big + 128, 256, NUSER, TU, nullptr, nullptr);
        attn_v4<<<(NNEWS + 15) / 16, 256, 0, stream>>>(
            q_news, kv_big, rp0, nullptr, nullptr, cl, agg_n, NNEWS, 0);

        // rel1 K/V (news src) -> kv_sm ; rel2 K/V (user src) -> kv_big (reuse, stream-ordered)
        gemm_v4<2, false, false, false, true><<<gbN, 256, 0, stream>>>(
            xn, wkf_l + 16384, wvf_l + 16384, bke_l + 128, bve_l + 128,
            kv_sm, kv_sm + 128, 256, NNEWS, 1, nullptr, nullptr);
        gemm_v4<2, false, false, false, true><<<gbU, 256, 0, stream>>>(
            xu, wkf_l + 32768, wvf_l + 32768, bke_l + 256, bve_l + 256,
            kv_big, kv_big + 128, 256, NUSER, TU, nullptr, nullptr);
        attn_v4<<<(NUSER + 15) / 16, 256, 0, stream>>>(
            q_user, kv_sm, rp1, kv_big, rp2, cl, agg_u, NUSER, 1);

        // output transform: relu(sig(skip)*(gelu(agg)@Wa + ba) + (1-sig)*x) [in-place safe]
        gemm_v4<1, true, true, true, false><<<gbU, 256, 0, stream>>>(
            agg_u, waf_l, nullptr, ba + (size_t)(l * 2 + 0) * 128, nullptr,
            out_user, nullptr, 128, NUSER, TU, skip + l * 2 + 0, xu);
        gemm_v4<1, true, true, true, false><<<gbN, 256, 0, stream>>>(
            agg_n, waf_l + 16384, nullptr, ba + (size_t)(l * 2 + 1) * 128, nullptr,
            out_news, nullptr, 128, NNEWS, 1, skip + l * 2 + 1, xn);
    }
    (void)in_sizes; (void)n_in; (void)out_size; (void)ws_size;
}

// Round 9
// 612.426 us; speedup vs baseline: 3.0373x; 1.1149x over previous
//
#include <hip/hip_runtime.h>
#include <cmath>

// ---------------- problem constants ----------------
constexpr int NUSER = 100000;
constexpr int NNEWS = 20000;
constexpr int CH    = 128;
constexpr int NE    = 250000;
constexpr int NTOT  = NNEWS + NUSER + NUSER;   // joint counter array (rel0|rel1|rel2)
constexpr int NSB   = (NTOT + 255) / 256;      // scan blocks = 860

typedef _Float16 f16x8 __attribute__((ext_vector_type(8)));
typedef _Float16 f16x4 __attribute__((ext_vector_type(4)));
typedef _Float16 f16x2 __attribute__((ext_vector_type(2)));
typedef float    f32x4 __attribute__((ext_vector_type(4)));

// ---------------- workspace layout (float units) ----------------
constexpr size_t OFF_QU  = 0;                                   // q_user fp16 [NUSER*128]
constexpr size_t OFF_QN  = OFF_QU  + (size_t)NUSER * 64;        // q_news fp16
constexpr size_t OFF_AGU = OFF_QN  + (size_t)NNEWS * 64;        // agg_user fp16 (gelu'd)
constexpr size_t OFF_AGN = OFF_AGU + (size_t)NUSER * 64;        // agg_news fp16 (gelu'd)
constexpr size_t OFF_KVB = OFF_AGN + (size_t)NNEWS * 64;        // kv_big fp16 [NUSER][256] (k|v interleaved)
constexpr size_t OFF_KVS = OFF_KVB + (size_t)NUSER * 128;       // kv_sm  fp16 [NNEWS][256]
constexpr size_t OFF_WF  = OFF_KVS + (size_t)NNEWS * 128;       // swizzled fp16 frags, BOTH layers (20 matrices)
constexpr size_t OFF_BE  = OFF_WF  + 20 * 8192;                 // bke[2][3][128] + bve[2][3][128] f32
constexpr size_t OFF_INT = OFF_BE  + 2 * 768;
// int offsets (relative, units: int)
constexpr size_t IO_CU   = 0;                    // joint counters [NTOT]
constexpr size_t IO_JRP  = IO_CU  + NTOT;        // joint row_ptr [NTOT+1]
constexpr size_t IO_BSUM = IO_JRP + NTOT + 1;    // scan partials [NSB]
constexpr size_t IO_BOFF = IO_BSUM + NSB;        // scan offsets  [NSB]
constexpr size_t IO_CL   = IO_BOFF + NSB;        // col (src per CSR slot) [3*NE]
constexpr size_t IO_RANK = IO_CL + 3 * NE;       // per-edge rank within dst [3*NE]

__device__ __forceinline__ float gelu_f(float x) {
    return 0.5f * x * (1.0f + erff(x * 0.70710678118654752440f));
}

// ---------------- swizzled-fragment dest index ----------------
// MFMA 16x16x32 fragment (lane,j): idx = lane&15, k = (lane>>4)*8 + j.
// Wf layout: [kt][ct][lane][j] contiguous -> coalesced b128 stage, conflict-free ds_read_b128.
__device__ __forceinline__ int frag_dest(int k, int col) {
    int kt = k >> 5, quad = (k >> 3) & 3, j = k & 7;
    int ct = col >> 4, m = col & 15;
    int lane = quad * 16 + m;
    return ((kt * 8 + ct) * 64 + lane) * 8 + j;
}

// ---------------- flat weight prep (both layers) + counter zeroing, one dispatch ----------------
constexpr int NEFF = 2 * 2 * 3 * 16384;   // 196608
constexpr int NCVT = 2 * 4 * 16384;       // 131072
constexpr int NBIA = 2 * 2 * 3 * 128;     // 1536
constexpr int NPREP = NEFF + NCVT + NBIA;

__global__ __launch_bounds__(256) void prep_weights_kernel(
    const float* __restrict__ Wk, const float* __restrict__ bk,
    const float* __restrict__ Wv, const float* __restrict__ bv,
    const float* __restrict__ Wq, const float* __restrict__ Wa,
    const float* __restrict__ a_rel, const float* __restrict__ m_rel,
    const float* __restrict__ p_rel,
    _Float16* __restrict__ wkf, float* __restrict__ bke,
    _Float16* __restrict__ wvf, float* __restrict__ bve,
    _Float16* __restrict__ wqf, _Float16* __restrict__ waf,
    int* __restrict__ cu)
{
    const float kscale = 0.17677669529663688f * 1.44269504088896340f;  // 1/sqrt(32)*log2(e)
    int idx = blockIdx.x * 256 + threadIdx.x;
    if (idx < NEFF) {
        int o = idx & 16383;
        int g = idx >> 14;          // (l*2+kind)*3 + r
        int r = g % 3, lk = g / 3, kind = lk & 1, l = lk >> 1;
        int st = (r == 1) ? 1 : 0;
        const float* W   = (kind ? Wv : Wk) + ((size_t)(l * 2 + st)) * 16384;
        const float* rel = (kind ? m_rel : a_rel) + ((size_t)(l * 3 + r)) * 4096;
        _Float16* Wf = (kind ? wvf : wkf) + ((size_t)(l * 3 + r)) * 16384;
        int k = o >> 7, col = o & 127, h = col >> 5, e = col & 31;
        const float* wrow = W + (size_t)k * 128 + h * 32;
        const float* rcol = rel + h * 1024 + e;
        float s = 0.f;
        #pragma unroll
        for (int d = 0; d < 32; ++d) s += wrow[d] * rcol[d * 32];
        if (kind == 0) s *= p_rel[(l * 3 + r) * 4 + h] * kscale;
        Wf[frag_dest(k, col)] = (_Float16)s;
    } else if (idx < NEFF + NCVT) {
        int t = idx - NEFF;
        int o = t & 16383;
        int b = t >> 14;            // l*4 + sub  (sub 0,1: Wq types; 2,3: Wa types)
        int l = b >> 2, sub = b & 3;
        const float* W;
        _Float16* Wf;
        if (sub < 2) { W = Wq + ((size_t)(l * 2 + sub)) * 16384;     Wf = wqf + ((size_t)(l * 2 + sub)) * 16384; }
        else         { W = Wa + ((size_t)(l * 2 + sub - 2)) * 16384; Wf = waf + ((size_t)(l * 2 + sub - 2)) * 16384; }
        int k = o >> 7, col = o & 127;
        Wf[frag_dest(k, col)] = (_Float16)W[o];
    } else if (idx < NPREP) {
        int t = idx - NEFF - NCVT;
        int col = t & 127;
        int g = t >> 7;
        int r = g % 3, lk = g / 3, kind = lk & 1, l = lk >> 1;
        int st = (r == 1) ? 1 : 0;
        const float* bi  = (kind ? bv : bk) + ((size_t)(l * 2 + st)) * 128;
        const float* rel = (kind ? m_rel : a_rel) + ((size_t)(l * 3 + r)) * 4096;
        float* be = (kind ? bve : bke) + (size_t)l * 384 + r * 128;
        int h = col >> 5, e = col & 31;
        float s = 0.f;
        #pragma unroll
        for (int d = 0; d < 32; ++d) s += bi[h * 32 + d] * rel[h * 1024 + d * 32 + e];
        if (kind == 0) s *= p_rel[(l * 3 + r) * 4 + h] * kscale;
        be[col] = s;
    } else if (idx < NPREP + NTOT) {
        cu[idx - NPREP] = 0;       // zero the CSR counters (fused: saves a dispatch)
    }
}

// ---------------- CSR build: hist + per-edge rank (atomics), scan, atomic-free fill ----------------
__global__ void histrank_kernel(const int* __restrict__ e0, const int* __restrict__ e1,
                                const int* __restrict__ e2, int* __restrict__ cu,
                                int* __restrict__ rank) {
    int idx = blockIdx.x * 256 + threadIdx.x;
    if (idx >= 3 * NE) return;
    int r = idx / NE, e = idx - r * NE;
    const int* ei = (r == 0) ? e0 : (r == 1) ? e1 : e2;
    int base = (r == 0) ? 0 : (r == 1) ? NNEWS : (NNEWS + NUSER);
    rank[idx] = atomicAdd(&cu[base + ei[NE + e]], 1);
}

__global__ __launch_bounds__(256) void scan_part_kernel(const int* __restrict__ cu,
                                                        int* __restrict__ bsum) {
    int i = blockIdx.x * 256 + threadIdx.x;
    int v = (i < NTOT) ? cu[i] : 0;
    #pragma unroll
    for (int o = 1; o < 64; o <<= 1) v += __shfl_xor(v, o);
    __shared__ int ws_[4];
    if ((threadIdx.x & 63) == 0) ws_[threadIdx.x >> 6] = v;
    __syncthreads();
    if (threadIdx.x == 0) bsum[blockIdx.x] = ws_[0] + ws_[1] + ws_[2] + ws_[3];
}

__global__ __launch_bounds__(1024) void scan_top_kernel(const int* __restrict__ bsum,
                                                        int* __restrict__ boff,
                                                        int* __restrict__ jrp) {
    __shared__ int wsum[16];
    int tid = threadIdx.x, lane = tid & 63, w = tid >> 6;
    int v = (tid < NSB) ? bsum[tid] : 0;
    int x = v;
    #pragma unroll
    for (int o = 1; o < 64; o <<= 1) { int y = __shfl_up(x, o); if (lane >= o) x += y; }
    if (lane == 63) wsum[w] = x;
    __syncthreads();
    if (tid < 16) {
        int t = wsum[tid];
        #pragma unroll
        for (int o = 1; o < 16; o <<= 1) { int y = __shfl_up(t, o); if (tid >= o) t += y; }
        wsum[tid] = t;
    }
    __syncthreads();
    int woff = w ? wsum[w - 1] : 0;
    if (tid < NSB) boff[tid] = woff + x - v;
    if (tid == 0) jrp[NTOT] = 3 * NE;
}

__global__ __launch_bounds__(256) void scan_fin_kernel(const int* __restrict__ cu,
                                                       const int* __restrict__ boff,
                                                       int* __restrict__ jrp) {
    __shared__ int wsum[4];
    int tid = threadIdx.x, lane = tid & 63, w = tid >> 6;
    int i = blockIdx.x * 256 + tid;
    int v = (i < NTOT) ? cu[i] : 0;
    int x = v;
    #pragma unroll
    for (int o = 1; o < 64; o <<= 1) { int y = __shfl_up(x, o); if (lane >= o) x += y; }
    if (lane == 63) wsum[w] = x;
    __syncthreads();
    int woff = 0;
    #pragma unroll
    for (int k = 0; k < 4; ++k) if (k < w) woff += wsum[k];
    int excl = boff[blockIdx.x] + woff + x - v;
    if (i < NTOT) jrp[i] = excl;
}

__global__ void fill_kernel(const int* __restrict__ e0, const int* __restrict__ e1,
                            const int* __restrict__ e2, const int* __restrict__ jrp,
                            const int* __restrict__ rank, int* __restrict__ cl) {
    int idx = blockIdx.x * 256 + threadIdx.x;
    if (idx >= 3 * NE) return;
    int r = idx / NE, e = idx - r * NE;
    const int* ei = (r == 0) ? e0 : (r == 1) ? e1 : e2;
    int base = (r == 0) ? 0 : (r == 1) ? NNEWS : (NNEWS + NUSER);
    int dst = ei[NE + e], src = ei[e];
    cl[jrp[base + dst] + rank[idx]] = src;   // no atomics (R8: fill3 = 46 us of atomic latency)
}

// ---------------- MFMA GEMM v4: LDS weights + T-tile loop ----------------
template<int NOUT, bool IN_HALF, bool GELU_IN, bool SKIP_OUT, bool OUT_HALF>
__global__ __launch_bounds__(256) void gemm_v4(
    const void* __restrict__ Ain,
    const _Float16* __restrict__ Wf0, const _Float16* __restrict__ Wf1,
    const float* __restrict__ b0, const float* __restrict__ b1,
    void* __restrict__ out0, void* __restrict__ out1, int ostride,
    int N, int T, const float* __restrict__ skipv, const float* __restrict__ Xold)
{
    __shared__ _Float16 sW[NOUT * 16384];   // 32 KB per weight matrix
    const int tid = threadIdx.x;

    for (int i = tid; i < NOUT * 2048; i += 256) {
        const _Float16* src = (NOUT == 1 || i < 2048) ? (Wf0 + (size_t)i * 8)
                                                      : (Wf1 + (size_t)(i - 2048) * 8);
        *(f16x8*)(sW + (size_t)i * 8) = *(const f16x8*)src;
    }
    __syncthreads();

    const int lane = tid & 63;
    const int m = lane & 15, quad = lane >> 4, wave = tid >> 6;

    float aS = 0.f, bSk = 0.f;
    if (SKIP_OUT) {
        float sv = skipv[0];
        aS = 1.0f / (1.0f + expf(-sv));
        bSk = 1.0f - aS;
    }

    for (int t = 0; t < T; ++t) {
        const int row0 = (blockIdx.x * T + t) * 64;
        if (row0 >= N) break;                       // block-uniform (no barriers inside)
        const int node  = row0 + wave * 16 + m;
        const int nodec = (node < N) ? node : (N - 1);

        f32x4 acc0[8], acc1[8];
        #pragma unroll
        for (int u = 0; u < 8; ++u) {
            acc0[u] = (f32x4){0.f, 0.f, 0.f, 0.f};
            if (NOUT > 1) acc1[u] = (f32x4){0.f, 0.f, 0.f, 0.f};
        }

        #pragma unroll
        for (int kt = 0; kt < 4; ++kt) {
            f16x8 xf;
            if (IN_HALF) {
                xf = *(const f16x8*)((const _Float16*)Ain + (size_t)nodec * 128 + kt * 32 + quad * 8);
                if (GELU_IN) {
                    #pragma unroll
                    for (int j = 0; j < 8; ++j) xf[j] = (_Float16)gelu_f((float)xf[j]);
                }
            } else {
                const float* Af = (const float*)Ain + (size_t)nodec * 128 + kt * 32 + quad * 8;
                f32x4 a0 = *(const f32x4*)Af;
                f32x4 a1 = *(const f32x4*)(Af + 4);
                if (GELU_IN) {
                    #pragma unroll
                    for (int j = 0; j < 4; ++j) { a0[j] = gelu_f(a0[j]); a1[j] = gelu_f(a1[j]); }
                }
                xf = (f16x8){(_Float16)a0[0], (_Float16)a0[1], (_Float16)a0[2], (_Float16)a0[3],
                             (_Float16)a1[0], (_Float16)a1[1], (_Float16)a1[2], (_Float16)a1[3]};
            }
            #pragma unroll
            for (int ct = 0; ct < 8; ++ct) {
                f16x8 wf0 = *(const f16x8*)(sW + ((kt * 8 + ct) * 64 + lane) * 8);
                acc0[ct] = __builtin_amdgcn_mfma_f32_16x16x32_f16(wf0, xf, acc0[ct], 0, 0, 0);
                if (NOUT > 1) {
                    f16x8 wf1 = *(const f16x8*)(sW + 16384 + ((kt * 8 + ct) * 64 + lane) * 8);
                    acc1[ct] = __builtin_amdgcn_mfma_f32_16x16x32_f16(wf1, xf, acc1[ct], 0, 0, 0);
                }
            }
        }

        if (node >= N) continue;

        #pragma unroll
        for (int ct = 0; ct < 8; ++ct) {
            int c = ct * 16 + quad * 4;      // out-channel base for this lane's 4 regs
            {
                f32x4 r = acc0[ct] + *(const f32x4*)(b0 + c);
                if (SKIP_OUT) {
                    f32x4 xo = *(const f32x4*)(Xold + (size_t)node * 128 + c);
                    #pragma unroll
                    for (int j = 0; j < 4; ++j) r[j] = fmaxf(aS * r[j] + bSk * xo[j], 0.f);
                }
                if (OUT_HALF) {
                    f16x4 h = {(_Float16)r[0], (_Float16)r[1], (_Float16)r[2], (_Float16)r[3]};
                    *(f16x4*)((_Float16*)out0 + (size_t)node * ostride + c) = h;
                } else {
                    *(f32x4*)((float*)out0 + (size_t)node * ostride + c) = r;
                }
            }
            if (NOUT > 1) {
                f32x4 r = acc1[ct] + *(const f32x4*)(b1 + c);
                f16x4 h = {(_Float16)r[0], (_Float16)r[1], (_Float16)r[2], (_Float16)r[3]};
                *(f16x4*)((_Float16*)out1 + (size_t)node * ostride + c) = h;
            }
        }
    }
}

// ---------------- attention v5: 4 nodes/wave, 2-edge unroll (ILP), gelu fused on store ----------------
// kv interleaved [node][k|v] fp16. Lane sub (0..15): channels sub*8..+7, head = sub>>2.
// w = exp2(score) (log2e folded into k_eff). agg := gelu(softmax-agg)  [epilogue GEMM eats it raw].
__global__ __launch_bounds__(256) void attn_v5(
    const _Float16* __restrict__ q,
    const _Float16* __restrict__ kv1, const int* __restrict__ rp1,
    const _Float16* __restrict__ kv2, const int* __restrict__ rp2,
    const int* __restrict__ cl,
    _Float16* __restrict__ agg, int Ndst, int two)
{
    int d = blockIdx.x * 16 + (threadIdx.x >> 4);   // 16 nodes per block (4 per wave)
    if (d >= Ndst) return;
    const int sub = threadIdx.x & 15;
    f16x8 qh = *(const f16x8*)(q + (size_t)d * 128 + sub * 8);
    float acc[8] = {0.f, 0.f, 0.f, 0.f, 0.f, 0.f, 0.f, 0.f};

    for (int rel = 0; rel < 1 + two; ++rel) {
        const _Float16* kv = rel ? kv2 : kv1;
        const int* rp = rel ? rp2 : rp1;
        int e0 = rp[d], e1 = rp[d + 1];
        float den = 0.f;
        float s[8] = {0.f, 0.f, 0.f, 0.f, 0.f, 0.f, 0.f, 0.f};
        int e = e0;
        for (; e + 1 < e1; e += 2) {                // two independent chains per iter
            int s0 = cl[e], s1 = cl[e + 1];
            const _Float16* r0 = kv + (size_t)s0 * 256;
            const _Float16* r1 = kv + (size_t)s1 * 256;
            f16x8 k0 = *(const f16x8*)(r0 + sub * 8);
            f16x8 v0 = *(const f16x8*)(r0 + 128 + sub * 8);
            f16x8 k1 = *(const f16x8*)(r1 + sub * 8);
            f16x8 v1 = *(const f16x8*)(r1 + 128 + sub * 8);
            float p0 = 0.f, p1 = 0.f;
#if __has_builtin(__builtin_amdgcn_fdot2)
            const f16x2* qp = (const f16x2*)&qh;
            const f16x2* a0 = (const f16x2*)&k0;
            const f16x2* a1 = (const f16x2*)&k1;
            #pragma unroll
            for (int j = 0; j < 4; ++j) {
                p0 = __builtin_amdgcn_fdot2(a0[j], qp[j], p0, false);
                p1 = __builtin_amdgcn_fdot2(a1[j], qp[j], p1, false);
            }
#else
            #pragma unroll
            for (int j = 0; j < 8; ++j) {
                p0 += (float)k0[j] * (float)qh[j];
                p1 += (float)k1[j] * (float)qh[j];
            }
#endif
            p0 += __shfl_xor(p0, 1); p1 += __shfl_xor(p1, 1);
            p0 += __shfl_xor(p0, 2); p1 += __shfl_xor(p1, 2);
            float w0 = exp2f(p0), w1 = exp2f(p1);
            den += w0 + w1;
            #pragma unroll
            for (int j = 0; j < 8; ++j) s[j] += w0 * (float)v0[j] + w1 * (float)v1[j];
        }
        if (e < e1) {
            int s0 = cl[e];
            const _Float16* r0 = kv + (size_t)s0 * 256;
            f16x8 k0 = *(const f16x8*)(r0 + sub * 8);
            f16x8 v0 = *(const f16x8*)(r0 + 128 + sub * 8);
            float p0 = 0.f;
#if __has_builtin(__builtin_amdgcn_fdot2)
            const f16x2* qp = (const f16x2*)&qh;
            const f16x2* a0 = (const f16x2*)&k0;
            #pragma unroll
            for (int j = 0; j < 4; ++j) p0 = __builtin_amdgcn_fdot2(a0[j], qp[j], p0, false);
#else
            #pragma unroll
            for (int j = 0; j < 8; ++j) p0 += (float)k0[j] * (float)qh[j];
#endif
            p0 += __shfl_xor(p0, 1);
            p0 += __shfl_xor(p0, 2);
            float w0 = exp2f(p0);
            den += w0;
            #pragma unroll
            for (int j = 0; j < 8; ++j) s[j] += w0 * (float)v0[j];
        }
        if (den > 0.f) {
            float inv = 1.f / den;
            #pragma unroll
            for (int j = 0; j < 8; ++j) acc[j] += s[j] * inv;
        }
    }

    f16x8 o;
    #pragma unroll
    for (int j = 0; j < 8; ++j) o[j] = (_Float16)gelu_f(acc[j]);   // gelu fused (epilogue is pure MFMA)
    *(f16x8*)(agg + (size_t)d * 128 + sub * 8) = o;
}

// ---------------- orchestration ----------------
extern "C" void kernel_launch(void* const* d_in, const int* in_sizes, int n_in,
                              void* d_out, int out_size, void* d_ws, size_t ws_size,
                              hipStream_t stream)
{
    const float* x_user = (const float*)d_in[0];
    const float* x_news = (const float*)d_in[1];
    const int* ei0 = (const int*)d_in[2];
    const int* ei1 = (const int*)d_in[3];
    const int* ei2 = (const int*)d_in[4];
    const float* Wk = (const float*)d_in[5];
    const float* bk = (const float*)d_in[6];
    const float* Wq = (const float*)d_in[7];
    const float* bq = (const float*)d_in[8];
    const float* Wv = (const float*)d_in[9];
    const float* bv = (const float*)d_in[10];
    const float* Wa = (const float*)d_in[11];
    const float* ba = (const float*)d_in[12];
    const float* skip = (const float*)d_in[13];
    const float* a_rel = (const float*)d_in[14];
    const float* m_rel = (const float*)d_in[15];
    const float* p_rel = (const float*)d_in[16];

    float* ws = (float*)d_ws;
    _Float16* q_user  = (_Float16*)(ws + OFF_QU);
    _Float16* q_news  = (_Float16*)(ws + OFF_QN);
    _Float16* agg_u   = (_Float16*)(ws + OFF_AGU);
    _Float16* agg_n   = (_Float16*)(ws + OFF_AGN);
    _Float16* kv_big  = (_Float16*)(ws + OFF_KVB);
    _Float16* kv_sm   = (_Float16*)(ws + OFF_KVS);
    _Float16* wkf = (_Float16*)(ws + OFF_WF);       // [2][3] matrices
    _Float16* wvf = wkf + 6 * 16384;                // [2][3]
    _Float16* wqf = wvf + 6 * 16384;                // [2][2]
    _Float16* waf = wqf + 4 * 16384;                // [2][2]
    float* bke = ws + OFF_BE;                       // [2][3][128]
    float* bve = bke + 768;
    int* ib   = (int*)(ws + OFF_INT);
    int* cu   = ib + IO_CU;
    int* jrp  = ib + IO_JRP;
    int* bsum = ib + IO_BSUM;
    int* boff = ib + IO_BOFF;
    int* cl   = ib + IO_CL;
    int* rank = ib + IO_RANK;
    const int* rp0 = jrp;
    const int* rp1 = jrp + NNEWS;
    const int* rp2 = jrp + NNEWS + NUSER;

    // ---- weight prep (both layers) + counter zero, one flat dispatch ----
    prep_weights_kernel<<<(NPREP + NTOT + 255) / 256, 256, 0, stream>>>(
        Wk, bk, Wv, bv, Wq, Wa, a_rel, m_rel, p_rel,
        wkf, bke, wvf, bve, wqf, waf, cu);

    // ---- CSR build: hist+rank (atomics) -> scan -> atomic-free fill ----
    int g3e = (3 * NE + 255) / 256;
    histrank_kernel<<<g3e, 256, 0, stream>>>(ei0, ei1, ei2, cu, rank);
    scan_part_kernel<<<NSB, 256, 0, stream>>>(cu, bsum);
    scan_top_kernel<<<1, 1024, 0, stream>>>(bsum, boff, jrp);
    scan_fin_kernel<<<NSB, 256, 0, stream>>>(cu, boff, jrp);
    fill_kernel<<<g3e, 256, 0, stream>>>(ei0, ei1, ei2, jrp, rank, cl);

    float* out_user = (float*)d_out;
    float* out_news = (float*)d_out + (size_t)NUSER * CH;

    constexpr int T1 = 2;   // NOUT=1 user GEMMs: 782 blocks (~3/CU)
    constexpr int T2 = 4;   // NOUT=2 user GEMMs: 64KB LDS caps 2 blocks/CU anyway
    int gbU1 = (NUSER + 64 * T1 - 1) / (64 * T1);
    int gbU2 = (NUSER + 64 * T2 - 1) / (64 * T2);
    int gbN  = (NNEWS + 63) / 64;                  // news: T=1 (keep TLP)

    for (int l = 0; l < 2; ++l) {
        const float* xu = l ? (const float*)out_user : x_user;
        const float* xn = l ? (const float*)out_news : x_news;
        _Float16* wkf_l = wkf + (size_t)l * 3 * 16384;
        _Float16* wvf_l = wvf + (size_t)l * 3 * 16384;
        _Float16* wqf_l = wqf + (size_t)l * 2 * 16384;
        _Float16* waf_l = waf + (size_t)l * 2 * 16384;
        float* bke_l = bke + (size_t)l * 384;
        float* bve_l = bve + (size_t)l * 384;

        // q projections (fp16, stride 128)
        gemm_v4<1, false, false, false, true><<<gbU1, 256, 0, stream>>>(
            xu, wqf_l, nullptr, bq + (size_t)(l * 2 + 0) * 128, nullptr,
            q_user, nullptr, 128, NUSER, T1, nullptr, nullptr);
        gemm_v4<1, false, false, false, true><<<gbN, 256, 0, stream>>>(
            xn, wqf_l + 16384, nullptr, bq + (size_t)(l * 2 + 1) * 128, nullptr,
            q_news, nullptr, 128, NNEWS, 1, nullptr, nullptr);

        // rel0 K/V (user src) -> kv_big, then news attention
        gemm_v4<2, false, false, false, true><<<gbU2, 256, 0, stream>>>(
            xu, wkf_l, wvf_l, bke_l, bve_l,
            kv_big, kv_big + 128, 256, NUSER, T2, nullptr, nullptr);
        attn_v5<<<(NNEWS + 15) / 16, 256, 0, stream>>>(
            q_news, kv_big, rp0, nullptr, nullptr, cl, agg_n, NNEWS, 0);

        // rel1 K/V (news src) -> kv_sm ; rel2 K/V (user src) -> kv_big (reuse, stream-ordered)
        gemm_v4<2, false, false, false, true><<<gbN, 256, 0, stream>>>(
            xn, wkf_l + 16384, wvf_l + 16384, bke_l + 128, bve_l + 128,
            kv_sm, kv_sm + 128, 256, NNEWS, 1, nullptr, nullptr);
        gemm_v4<2, false, false, false, true><<<gbU2, 256, 0, stream>>>(
            xu, wkf_l + 32768, wvf_l + 32768, bke_l + 256, bve_l + 256,
            kv_big, kv_big + 128, 256, NUSER, T2, nullptr, nullptr);
        attn_v5<<<(NUSER + 15) / 16, 256, 0, stream>>>(
            q_user, kv_sm, rp1, kv_big, rp2, cl, agg_u, NUSER, 1);

        // output transform: relu(sig(skip)*(gelu_agg@Wa + ba) + (1-sig)*x)  [gelu already in agg]
        gemm_v4<1, true, false, true, false><<<gbU1, 256, 0, stream>>>(
            agg_u, waf_l, nullptr, ba + (size_t)(l * 2 + 0) * 128, nullptr,
            out_user, nullptr, 128, NUSER, T1, skip + l * 2 + 0, xu);
        gemm_v4<1, true, false, true, false><<<gbN, 256, 0, stream>>>(
            agg_n, waf_l + 16384, nullptr, ba + (size_t)(l * 2 + 1) * 128, nullptr,
            out_news, nullptr, 128, NNEWS, 1, skip + l * 2 + 1, xn);
    }
    (void)in_sizes; (void)n_in; (void)out_size; (void)ws_size;
}